// Round 6
// baseline (1314.246 us; speedup 1.0000x reference)
//
#include <hip/hip_runtime.h>
#include <math.h>

#define NB 64      // batch
#define TTX 256    // text timesteps
#define TTP 16     // topic timesteps
#define EE 300     // embedding dim
#define HH 512     // hidden
#define SENT 0x7FC0DEADu   // NaN-payload sentinel; real h can never be NaN

// ---------------------------------------------------------------------------
// init: poison all 4 h-ring slots (must run each call: graph replays must be
// deterministic and the ring ends a call full of real values)
// ---------------------------------------------------------------------------
__global__ void sd_init_ring(unsigned* __restrict__ hring) {
  hring[blockIdx.x * blockDim.x + threadIdx.x] = SENT;  // grid == 4*NB*HH
}

// ---------------------------------------------------------------------------
// xproj: out[t*64+b][c] = sum_k emb[idx[b][t]][k] * W[k][c'] + bias[c']
// (unchanged)
// ---------------------------------------------------------------------------
__global__ __launch_bounds__(256) void sd_xproj(
    const int* __restrict__ idx, int T,
    const float* __restrict__ emb,
    const float* __restrict__ Wz, const float* __restrict__ Wo,
    const float* __restrict__ bz, const float* __restrict__ bo,
    float* __restrict__ xp)
{
  __shared__ int tok[64];
  __shared__ alignas(16) float As[12][64];
  __shared__ alignas(16) float Bs[12][64];

  const int tid = threadIdx.x;
  const int t   = blockIdx.x;
  const int c0  = blockIdx.y * 64;

  if (tid < 64) tok[tid] = idx[tid * T + t];

  const float* Wsel = (c0 < 512) ? Wz : Wo;
  const float* bsel = (c0 < 512) ? bz : bo;
  const int cc0 = (c0 < 512) ? c0 : (c0 - 512);

  const int tx = tid & 15;
  const int ty = tid >> 4;

  float acc[4][4];
#pragma unroll
  for (int i = 0; i < 4; ++i)
#pragma unroll
    for (int j = 0; j < 4; ++j) acc[i][j] = 0.f;

  __syncthreads();

  const int r   = tid & 63;
  const int k0l = tid >> 6;

  for (int kk = 0; kk < EE; kk += 12) {
    const size_t erow = (size_t)tok[r] * EE + kk + k0l;
    float a0 = emb[erow + 0];
    float a1 = emb[erow + 4];
    float a2 = emb[erow + 8];
    const int j = tid & 63;
    float b0v = Wsel[(size_t)(kk + k0l + 0) * HH + cc0 + j];
    float b1v = Wsel[(size_t)(kk + k0l + 4) * HH + cc0 + j];
    float b2v = Wsel[(size_t)(kk + k0l + 8) * HH + cc0 + j];
    __syncthreads();
    As[k0l + 0][r] = a0;  As[k0l + 4][r] = a1;  As[k0l + 8][r] = a2;
    Bs[k0l + 0][j] = b0v; Bs[k0l + 4][j] = b1v; Bs[k0l + 8][j] = b2v;
    __syncthreads();
#pragma unroll
    for (int k = 0; k < 12; ++k) {
      float4 av = *(const float4*)&As[k][ty * 4];
      float4 bv = *(const float4*)&Bs[k][tx * 4];
      acc[0][0] += av.x * bv.x; acc[0][1] += av.x * bv.y; acc[0][2] += av.x * bv.z; acc[0][3] += av.x * bv.w;
      acc[1][0] += av.y * bv.x; acc[1][1] += av.y * bv.y; acc[1][2] += av.y * bv.z; acc[1][3] += av.y * bv.w;
      acc[2][0] += av.z * bv.x; acc[2][1] += av.z * bv.y; acc[2][2] += av.z * bv.z; acc[2][3] += av.z * bv.w;
      acc[3][0] += av.w * bv.x; acc[3][1] += av.w * bv.y; acc[3][2] += av.w * bv.z; acc[3][3] += av.w * bv.w;
    }
  }

  const float4 bias4 = *(const float4*)&bsel[cc0 + tx * 4];
#pragma unroll
  for (int i = 0; i < 4; ++i) {
    const size_t row = (size_t)t * 64 + (ty * 4 + i);
    float4 o;
    o.x = acc[i][0] + bias4.x;
    o.y = acc[i][1] + bias4.y;
    o.z = acc[i][2] + bias4.z;
    o.w = acc[i][3] + bias4.w;
    *(float4*)&xp[row * 1024 + c0 + tx * 4] = o;
  }
}

// ---------------------------------------------------------------------------
// Persistent recurrence kernel — round-4 shape (512 thr = 8 waves = 2/SIMD,
// the empirically best TLP point) + wave-private poll + ONE sync per step.
//
//   256 blocks = 16 batch-groups x 16 dim-slices. Wave wv (0..7) owns
//   k-slice [wv*64, wv*64+64) = the stripes produced by blocks 2wv, 2wv+1
//   of this group. wreg[64] per lane.
//
//   Per step:
//     - wave wv polls ONLY its own 256 h-words (2 x u64 per lane) of slot
//       u&3 until != SENT, stages into its PRIVATE h_s region (no cross-wave
//       dependency pre-sync; same-wave RAW ordered by lgkmcnt)
//     - FMA over its 64-k slice, partials to red[cur]
//     - ONE __syncthreads
//     - writers (tid<128): poison own stripe of slot (u-1)&3, reduce 8x2
//       partials, gates, s_waitcnt vmcnt(1), store h(u+1) to slot (u+1)&3
//
//   Ring-protocol proofs:
//   * Recycle safety: block B's sync(u) requires all 8 waves of B to have
//     observed slot u&3 values from ALL 16 producer blocks => every producer
//     Pj passed its sync(u-1) => Pj's reader-wave of B's stripe finished its
//     slot-(u-1) reads. So B's post-sync(u) poison of its own stripe in slot
//     (u-1)&3 is safe.
//   * Stale-real safety: at step u, vmcnt(1) drains everything except the
//     just-issued step-u poison (different slot). The step-(u-2) poison of
//     slot (u+1)&3 is older => retired at the coherence point before the
//     real h(u+1) store issues; MALL same-address order does the rest.
//   * LDS safety with ONE sync and 2-deep buffers: writers read h_s[cur]
//     (hprev) and red[cur] after sync(u), as part of the step-u tail. Any
//     wave's next write of buffer `cur` happens in step u+2, which is after
//     sync(u+1) — and sync(u+1) cannot complete until the writer waves
//     arrive, i.e. after their step-u tail reads are done.
//
//   96KB LDS pad pins 1 block/CU -> all 256 blocks co-resident (spin-safe).
// ---------------------------------------------------------------------------
__global__ __launch_bounds__(512) void sd_recur(
    const float* __restrict__ tWz, const float* __restrict__ tWo,
    const float* __restrict__ pWz, const float* __restrict__ pWo,
    const float* __restrict__ xp_text, const float* __restrict__ xp_topic,
    float* __restrict__ text_out, unsigned* __restrict__ hring,
    float* __restrict__ topic_h)
{
  __shared__ alignas(16) float smem[24576];  // 96KB pad -> exactly 1 block/CU
  float* h_s = smem;          // [2][8 wv][4 row][64 k]
  float* red = smem + 4096;   // [2][8 kq][2 gt][4 row][32 d]

  const int tid = threadIdx.x;
  const int bid = blockIdx.x;
  const int x = bid & 7;           // XCD (heuristic placement)
  const int q = bid >> 3;
  const int g = x + 8 * (q >> 4);  // batch group 0..15
  const int slice = q & 15;        // dim slice 0..15
  const int b0 = g * 4;
  const int c_base = slice * 32;

  const int wv = tid >> 6;         // wave id = k-eighth (0..7)
  const int lane = tid & 63;
  const int gt = lane >> 5;        // 0 = z gate, 1 = o gate
  const int d = lane & 31;
  const int c = c_base + d;

  const int pr = lane >> 4;        // poll: row 0..3
  const int pi = lane & 15;        // poll: 4-word chunk index

  const int bi_w = tid >> 5;       // writer mapping (tid<128): batch row 0..3
  const int dw = tid & 31;

  // writer thread's private ring word offset (within a slot)
  const size_t wslot_off = (size_t)(b0 + bi_w) * HH + c_base + dw;
  // writer's hprev location in staged LDS (see layout note below)
  const int hprev_idx = (slice >> 1) * 256 + bi_w * 64 + (slice & 1) * 32 + dw;

  int u = 0;  // global step counter across both phases

  for (int ph = 0; ph < 2; ++ph) {
    const float* Wg = gt ? (ph ? pWo : tWo) : (ph ? pWz : tWz);
    const float* xp = ph ? xp_topic : xp_text;
    const int T = ph ? TTP : TTX;

    // this lane's W h-part column slice (k-eighth) into registers
    float wreg[64];
#pragma unroll
    for (int kk = 0; kk < 64; ++kk)
      wreg[kk] = Wg[(size_t)(EE + wv * 64 + kk) * HH + c];

    for (int t = 0; t < T; ++t, ++u) {
      const int cur = u & 1;
      const bool do_poll = (u > 0);
      const bool use_h   = (t > 0);

      // xp prefetch early (latency hidden under poll + FMA)
      float xpz = 0.f, xpo = 0.f;
      if (tid < 128) {
        const float* xpr = xp + ((size_t)t * 64 + (b0 + bi_w)) * 1024 + c_base + dw;
        xpz = xpr[0];
        xpo = xpr[512];
      }

      if (do_poll) {
        // wave-private poll: this wave's 256 words = 4 words/lane (2 x u64).
        // Layout staged per wave: [4 row][64 k] at h_s[cur][wv*256].
        const unsigned long long* src64 = (const unsigned long long*)
            (hring + (size_t)(u & 3) * NB * HH + (size_t)(b0 + pr) * HH + wv * 64 + pi * 4);
        unsigned long long va, vb;
        for (;;) {
          va = __hip_atomic_load(src64 + 0, __ATOMIC_RELAXED, __HIP_MEMORY_SCOPE_AGENT);
          vb = __hip_atomic_load(src64 + 1, __ATOMIC_RELAXED, __HIP_MEMORY_SCOPE_AGENT);
          if ((unsigned)va != SENT && (unsigned)(va >> 32) != SENT &&
              (unsigned)vb != SENT && (unsigned)(vb >> 32) != SENT) break;
          __builtin_amdgcn_s_sleep(1);
        }
        float4 hv4;
        hv4.x = __uint_as_float((unsigned)va);
        hv4.y = __uint_as_float((unsigned)(va >> 32));
        hv4.z = __uint_as_float((unsigned)vb);
        hv4.w = __uint_as_float((unsigned)(vb >> 32));
        *(float4*)&h_s[cur * 2048 + wv * 256 + pr * 64 + pi * 4] = hv4;
        // no sync needed before FMA: only this wave touches this region
        // pre-sync (writers read other regions strictly post-sync)
      }

      if (use_h) {
        float acc0 = 0.f, acc1 = 0.f, acc2 = 0.f, acc3 = 0.f;
        const float* hq = &h_s[cur * 2048 + wv * 256];  // [4 row][64 k]
#pragma unroll
        for (int k4 = 0; k4 < 16; ++k4) {
          const float w0 = wreg[4 * k4 + 0], w1 = wreg[4 * k4 + 1];
          const float w2 = wreg[4 * k4 + 2], w3 = wreg[4 * k4 + 3];
          float4 h0v = *(const float4*)(hq + 0 * 64 + 4 * k4);
          float4 h1v = *(const float4*)(hq + 1 * 64 + 4 * k4);
          float4 h2v = *(const float4*)(hq + 2 * 64 + 4 * k4);
          float4 h3v = *(const float4*)(hq + 3 * 64 + 4 * k4);
          acc0 += h0v.x * w0 + h0v.y * w1 + h0v.z * w2 + h0v.w * w3;
          acc1 += h1v.x * w0 + h1v.y * w1 + h1v.z * w2 + h1v.w * w3;
          acc2 += h2v.x * w0 + h2v.y * w1 + h2v.z * w2 + h2v.w * w3;
          acc3 += h3v.x * w0 + h3v.y * w1 + h3v.z * w2 + h3v.w * w3;
        }
        float* rp = &red[cur * 2048 + ((wv * 2 + gt) * 4) * 32 + d];
        rp[0 * 32] = acc0; rp[1 * 32] = acc1; rp[2 * 32] = acc2; rp[3 * 32] = acc3;
      }

      __syncthreads();  // single sync: all polls/stages/partials visible

      if (tid < 128) {
        // poison own stripe of slot (u-1)&3 (safe post-sync; header proof)
        if (do_poll)
          __hip_atomic_store(&hring[(size_t)((u - 1) & 3) * NB * HH + wslot_off],
                             SENT, __ATOMIC_RELAXED, __HIP_MEMORY_SCOPE_AGENT);

        float zp = 0.f, op = 0.f;
        float hprev = 0.f;
        if (use_h) {
#pragma unroll
          for (int k2 = 0; k2 < 8; ++k2) {
            zp += red[cur * 2048 + ((k2 * 2 + 0) * 4 + bi_w) * 32 + dw];
            op += red[cur * 2048 + ((k2 * 2 + 1) * 4 + bi_w) * 32 + dw];
          }
          hprev = h_s[cur * 2048 + hprev_idx];
        }
        const float a = zp + xpz;
        const float z = 1.f / (1.f + __expf(-a));
        const float bv = op + xpo;
        const float ab = fabsf(bv);
        const float e2 = __expf(-2.f * ab);
        const float htl = __builtin_copysignf((1.f - e2) / (1.f + e2), bv);
        const float hn = (1.f - z) * hprev + z * htl;

        // drain everything except this step's own poison (last-issued vmem):
        // orders the step-(u-2) same-address poison before the real store
        asm volatile("s_waitcnt vmcnt(1)" ::: "memory");
        __hip_atomic_store(&hring[(size_t)((u + 1) & 3) * NB * HH + wslot_off],
                           __float_as_uint(hn), __ATOMIC_RELAXED, __HIP_MEMORY_SCOPE_AGENT);
        if (ph == 0)
          text_out[((size_t)(b0 + bi_w) * TTX + t) * HH + c_base + dw] = hn;
        else if (t == T - 1)
          topic_h[(size_t)(b0 + bi_w) * HH + c_base + dw] = hn;
      }
      // no trailing barrier: 2-deep h_s/red tolerates one-phase skew
    }
  }
}

// ---------------------------------------------------------------------------
// attention: scores -> softmax weights (output) -> context  (unchanged)
// ---------------------------------------------------------------------------
__global__ __launch_bounds__(256) void sd_att(
    const float* __restrict__ text_out, const float* __restrict__ topic_h,
    const float* __restrict__ att_W, const float* __restrict__ att_b,
    float* __restrict__ context, float* __restrict__ weights_out)
{
  __shared__ alignas(16) float aw[1024];
  __shared__ float sred[256];
  __shared__ float wsh[256];
  const int b = blockIdx.x, tid = threadIdx.x;

  for (int i = tid; i < 1024; i += 256) aw[i] = att_W[i];
  __syncthreads();

  float part = 0.f;
  for (int i = tid; i < 512; i += 256) part += topic_h[(size_t)b * HH + i] * aw[512 + i];
  sred[tid] = part;
  __syncthreads();
  for (int s = 128; s > 0; s >>= 1) { if (tid < s) sred[tid] += sred[tid + s]; __syncthreads(); }
  const float cb = sred[0] + att_b[0];
  __syncthreads();

  const float* row = text_out + ((size_t)b * TTX + tid) * HH;
  float sc = cb;
  for (int d4 = 0; d4 < 128; ++d4) {
    float4 v = ((const float4*)row)[d4];
    float4 w4 = ((const float4*)aw)[d4];
    sc += v.x * w4.x + v.y * w4.y + v.z * w4.z + v.w * w4.w;
  }
  sred[tid] = sc; __syncthreads();
  for (int s = 128; s > 0; s >>= 1) { if (tid < s) sred[tid] = fmaxf(sred[tid], sred[tid + s]); __syncthreads(); }
  const float m = sred[0];
  __syncthreads();
  const float e = expf(sc - m);
  sred[tid] = e; __syncthreads();
  for (int s = 128; s > 0; s >>= 1) { if (tid < s) sred[tid] += sred[tid + s]; __syncthreads(); }
  const float wv = e / sred[0];
  wsh[tid] = wv;
  weights_out[(size_t)b * TTX + tid] = wv;
  __syncthreads();

  for (int rep = 0; rep < 2; ++rep) {
    const int dcol = rep * 256 + tid;
    float accc = 0.f;
    const float* base = text_out + (size_t)b * TTX * HH + dcol;
    for (int t2 = 0; t2 < TTX; ++t2) accc += wsh[t2] * base[(size_t)t2 * HH];
    context[(size_t)b * HH + dcol] = accc;
  }
}

// ---------------------------------------------------------------------------
// FC head: feat=[context, topic_h] -> relu(fc1) -> fc2 logits  (unchanged)
// ---------------------------------------------------------------------------
__global__ __launch_bounds__(256) void sd_fc(
    const float* __restrict__ context, const float* __restrict__ topic_h,
    const float* __restrict__ fc1_W, const float* __restrict__ fc1_b,
    const float* __restrict__ fc2_W, const float* __restrict__ fc2_b,
    float* __restrict__ logits)
{
  __shared__ alignas(16) float feat[1024];
  __shared__ float hid[512];
  const int b = blockIdx.x, tid = threadIdx.x;

  for (int i = tid; i < 512; i += 256) {
    feat[i]       = context[(size_t)b * HH + i];
    feat[512 + i] = topic_h[(size_t)b * HH + i];
  }
  __syncthreads();

  for (int rep = 0; rep < 2; ++rep) {
    const int dcol = rep * 256 + tid;
    float a = fc1_b[dcol];
#pragma unroll 4
    for (int j = 0; j < 1024; ++j) a += feat[j] * fc1_W[(size_t)j * HH + dcol];
    hid[dcol] = fmaxf(a, 0.f);
  }
  __syncthreads();

  float p0 = 0.f, p1 = 0.f, p2 = 0.f;
  for (int dv = tid; dv < 512; dv += 256) {
    const float hv = hid[dv];
    p0 += hv * fc2_W[dv * 3 + 0];
    p1 += hv * fc2_W[dv * 3 + 1];
    p2 += hv * fc2_W[dv * 3 + 2];
  }
  feat[tid] = p0; feat[256 + tid] = p1; feat[512 + tid] = p2;
  __syncthreads();
  for (int s = 128; s > 0; s >>= 1) {
    if (tid < s) {
      feat[tid] += feat[tid + s];
      feat[256 + tid] += feat[256 + tid + s];
      feat[512 + tid] += feat[512 + tid + s];
    }
    __syncthreads();
  }
  if (tid < 3) logits[b * 3 + tid] = feat[tid * 256] + fc2_b[tid];
}

// ---------------------------------------------------------------------------
extern "C" void kernel_launch(void* const* d_in, const int* in_sizes, int n_in,
                              void* d_out, int out_size, void* d_ws, size_t ws_size,
                              hipStream_t stream) {
  const int*   text  = (const int*)d_in[0];
  const int*   topic = (const int*)d_in[1];
  const float* emb   = (const float*)d_in[2];
  const float* tWz   = (const float*)d_in[3];
  const float* tbz   = (const float*)d_in[4];
  const float* tWo   = (const float*)d_in[5];
  const float* tbo   = (const float*)d_in[6];
  const float* pWz   = (const float*)d_in[7];
  const float* pbz   = (const float*)d_in[8];
  const float* pWo   = (const float*)d_in[9];
  const float* pbo   = (const float*)d_in[10];
  const float* attW  = (const float*)d_in[11];
  const float* attb  = (const float*)d_in[12];
  const float* fc1W  = (const float*)d_in[13];
  const float* fc1b  = (const float*)d_in[14];
  const float* fc2W  = (const float*)d_in[15];
  const float* fc2b  = (const float*)d_in[16];

  float* out = (float*)d_out;            // [0,192): logits, [192,+16384): weights
  float* ws  = (float*)d_ws;

  float* xp_text  = ws;                                    // 256*64*1024
  float* xp_topic = xp_text + (size_t)TTX * 64 * 1024;     // 16*64*1024
  float* text_o   = xp_topic + (size_t)TTP * 64 * 1024;    // 64*256*512
  float* topic_hv = text_o + (size_t)NB * TTX * HH;        // 64*512
  float* ctx      = topic_hv + (size_t)NB * HH;            // 64*512
  unsigned* hring = (unsigned*)(ctx + (size_t)NB * HH);    // 4*64*512 u32

  sd_init_ring<<<dim3(4 * NB * HH / 256), dim3(256), 0, stream>>>(hring);
  sd_xproj<<<dim3(TTX, 16), dim3(256), 0, stream>>>(text, TTX, emb, tWz, tWo, tbz, tbo, xp_text);
  sd_xproj<<<dim3(TTP, 16), dim3(256), 0, stream>>>(topic, TTP, emb, pWz, pWo, pbz, pbo, xp_topic);
  sd_recur<<<dim3(256), dim3(512), 0, stream>>>(tWz, tWo, pWz, pWo, xp_text, xp_topic,
                                                text_o, hring, topic_hv);
  sd_att<<<dim3(64), dim3(256), 0, stream>>>(text_o, topic_hv, attW, attb, ctx, out + 192);
  sd_fc<<<dim3(64), dim3(256), 0, stream>>>(ctx, topic_hv, fc1W, fc1b, fc2W, fc2b, out);
}

// Round 7
// 866.881 us; speedup vs baseline: 1.5161x; 1.5161x over previous
//
#include <hip/hip_runtime.h>
#include <math.h>

#define NB 64      // batch
#define TTX 256    // text timesteps
#define TTP 16     // topic timesteps
#define EE 300     // embedding dim
#define HH 512     // hidden
#define SENT 0x7FC0DEADu   // NaN-payload sentinel; real h can never be NaN

typedef __attribute__((ext_vector_type(4))) float f32x4;
typedef __attribute__((ext_vector_type(8))) short short8;

__device__ __forceinline__ unsigned short bf16cvt(float f) {
  unsigned u = __float_as_uint(f);
  u += 0x7FFFu + ((u >> 16) & 1u);   // RNE
  return (unsigned short)(u >> 16);
}

// ---------------------------------------------------------------------------
// init: poison all 4 h-ring slots (every call: graph replays deterministic)
// ---------------------------------------------------------------------------
__global__ void sd_init_ring(unsigned* __restrict__ hring) {
  hring[blockIdx.x * blockDim.x + threadIdx.x] = SENT;  // grid == 4*NB*HH
}

// ---------------------------------------------------------------------------
// prep: B_T[c][k] bf16, c in [0,1024) (z cols 0-511, o cols 512-1023),
// k in [0,320), zero-padded k >= 300. Runs every call (deterministic).
// ---------------------------------------------------------------------------
__global__ __launch_bounds__(256) void sd_prep_bt(
    const float* __restrict__ Wz, const float* __restrict__ Wo,
    unsigned short* __restrict__ Bt)
{
  const int i = blockIdx.x * blockDim.x + threadIdx.x;  // [0, 1024*320)
  const int k = i % 320;
  const int c = i / 320;
  const float* W = (c < 512) ? Wz : Wo;
  const float v = (k < 300) ? W[(size_t)k * HH + (c & 511)] : 0.f;
  Bt[i] = bf16cvt(v);
}

// ---------------------------------------------------------------------------
// xproj via MFMA bf16: block = (timestep t, 256-col tile).
//   A = emb[tok[0..63]][0..300) gathered -> LDS bf16 [64 m][328 k] (pad 0).
//   B = Bt[c][k] streamed from L2 as per-lane b128 fragments.
//   4 waves; wave w owns cols [w*64, w*64+64) (4 n-subtiles), all 4 m-subtiles.
//   Fragments: A row = lane&15, B col = lane&15, k-slots = contiguous 8 at
//   8*(lane>>4) for BOTH operands (slot-consistent => sum over k correct).
//   C/D: col = lane&15, row = (lane>>4)*4 + reg  [m89-verified].
// ---------------------------------------------------------------------------
__global__ __launch_bounds__(256) void sd_xproj_mfma(
    const int* __restrict__ idx, int T,
    const float* __restrict__ emb,
    const unsigned short* __restrict__ Bt,
    const float* __restrict__ bz, const float* __restrict__ bo,
    float* __restrict__ xp)
{
  __shared__ alignas(16) unsigned short Als[64 * 328];
  __shared__ int tok[64];

  const int tid = threadIdx.x;
  const int t   = blockIdx.x;
  const int c0  = blockIdx.y * 256;

  if (tid < 64) tok[tid] = idx[tid * T + t];
  __syncthreads();

  // gather + fp32->bf16: 4 threads per row, stride-4 over 75 float4 chunks
  {
    const int m  = tid >> 2;
    const int qt = tid & 3;
    const float* er = emb + (size_t)tok[m] * EE;
    unsigned short* ar = Als + m * 328;
    for (int j = qt; j < 75; j += 4) {
      const float4 v = *(const float4*)(er + 4 * j);
      ushort4 o;
      o.x = bf16cvt(v.x); o.y = bf16cvt(v.y);
      o.z = bf16cvt(v.z); o.w = bf16cvt(v.w);
      *(ushort4*)(ar + 4 * j) = o;
    }
    if (qt == 0) {
      for (int k = 300; k < 328; ++k) ar[k] = 0;
    }
  }
  __syncthreads();

  const int w  = tid >> 6;   // wave 0..3 -> col range w*64
  const int l  = tid & 63;
  const int lr = l & 15;     // row (A) / col (B,D) within subtile
  const int lg = l >> 4;     // k-slot group

  f32x4 acc[4][4];
#pragma unroll
  for (int ms = 0; ms < 4; ++ms)
#pragma unroll
    for (int ns = 0; ns < 4; ++ns)
      acc[ms][ns] = (f32x4){0.f, 0.f, 0.f, 0.f};

  const unsigned short* bbase = Bt + ((size_t)(c0 + w * 64 + lr)) * 320 + 8 * lg;

#pragma unroll 2
  for (int kc = 0; kc < 10; ++kc) {
    short8 bfr[4];
#pragma unroll
    for (int ns = 0; ns < 4; ++ns)
      bfr[ns] = *reinterpret_cast<const short8*>(bbase + (size_t)ns * 16 * 320 + kc * 32);
    short8 afr[4];
#pragma unroll
    for (int ms = 0; ms < 4; ++ms)
      afr[ms] = *reinterpret_cast<const short8*>(Als + (ms * 16 + lr) * 328 + kc * 32 + 8 * lg);
#pragma unroll
    for (int ms = 0; ms < 4; ++ms)
#pragma unroll
      for (int ns = 0; ns < 4; ++ns)
        acc[ms][ns] = __builtin_amdgcn_mfma_f32_16x16x32_bf16(afr[ms], bfr[ns], acc[ms][ns], 0, 0, 0);
  }

#pragma unroll
  for (int ns = 0; ns < 4; ++ns) {
    const int cg = c0 + w * 64 + ns * 16 + lr;
    const float bias = (cg < 512) ? bz[cg] : bo[cg - 512];
#pragma unroll
    for (int ms = 0; ms < 4; ++ms) {
#pragma unroll
      for (int r = 0; r < 4; ++r) {
        const int row = ms * 16 + lg * 4 + r;
        xp[((size_t)t * 64 + row) * 1024 + cg] = acc[ms][ns][r] + bias;
      }
    }
  }
}

// ---------------------------------------------------------------------------
// Persistent recurrence kernel — EXACT round-4 structure (empirically best:
// 670us, VALUBusy 50%). 512 thr = 8 waves = 2/SIMD; block-wide sentinel-ring
// poll; 2 syncs/step; vmcnt(0) before the real h-store.
//   256 blocks = 16 batch-groups x 16 dim-slices. Wave = k-eighth, wreg[64].
//   Ring proofs as in rounds 3-4 (recycle-after-poll-success; poison ordered
//   ahead of real store via vmcnt drain + same-address MALL order).
// ---------------------------------------------------------------------------
__global__ __launch_bounds__(512) void sd_recur(
    const float* __restrict__ tWz, const float* __restrict__ tWo,
    const float* __restrict__ pWz, const float* __restrict__ pWo,
    const float* __restrict__ xp_text, const float* __restrict__ xp_topic,
    float* __restrict__ text_out, unsigned* __restrict__ hring,
    float* __restrict__ topic_h)
{
  __shared__ alignas(16) float h_s[2][4 * HH];   // staged h rows, double-buffered
  __shared__ alignas(16) float red[2][2048];     // [8 kq][2 gt][4 row][32 d], dbuf

  const int tid = threadIdx.x;
  const int bid = blockIdx.x;
  const int x = bid & 7;           // XCD (heuristic placement)
  const int q = bid >> 3;
  const int g = x + 8 * (q >> 4);  // batch group 0..15
  const int slice = q & 15;        // dim slice 0..15
  const int b0 = g * 4;
  const int c_base = slice * 32;

  const int wv = tid >> 6;         // wave id = k-eighth (0..7)
  const int lane = tid & 63;
  const int gt = lane >> 5;        // 0 = z gate, 1 = o gate
  const int d = lane & 31;
  const int c = c_base + d;

  const int bi_w = tid >> 5;       // writer mapping (tid<128): batch row 0..3
  const int dw = tid & 31;

  const size_t wslot_off = (size_t)(b0 + bi_w) * HH + c_base + dw;

  int u = 0;  // global step counter across both phases

  for (int ph = 0; ph < 2; ++ph) {
    const float* Wg = gt ? (ph ? pWo : tWo) : (ph ? pWz : tWz);
    const float* xp = ph ? xp_topic : xp_text;
    const int T = ph ? TTP : TTX;

    float wreg[64];
#pragma unroll
    for (int kk = 0; kk < 64; ++kk)
      wreg[kk] = Wg[(size_t)(EE + wv * 64 + kk) * HH + c];

    for (int t = 0; t < T; ++t, ++u) {
      const int cur = u & 1;
      const bool do_poll = (u > 0);
      const bool use_h   = (t > 0);

      float xpz = 0.f, xpo = 0.f;
      if (tid < 128) {
        const float* xpr = xp + ((size_t)t * 64 + (b0 + bi_w)) * 1024 + c_base + dw;
        xpz = xpr[0];
        xpo = xpr[512];
      }

      if (do_poll) {
        // block-wide poll-stage: 2048 words of slot u&3, 4 words/thread
        const unsigned* src = hring + (size_t)(u & 3) * NB * HH + (size_t)b0 * HH;
        unsigned v0, v1, v2, v3;
        for (;;) {
          v0 = __hip_atomic_load(&src[tid + 0 * 512], __ATOMIC_RELAXED, __HIP_MEMORY_SCOPE_AGENT);
          v1 = __hip_atomic_load(&src[tid + 1 * 512], __ATOMIC_RELAXED, __HIP_MEMORY_SCOPE_AGENT);
          v2 = __hip_atomic_load(&src[tid + 2 * 512], __ATOMIC_RELAXED, __HIP_MEMORY_SCOPE_AGENT);
          v3 = __hip_atomic_load(&src[tid + 3 * 512], __ATOMIC_RELAXED, __HIP_MEMORY_SCOPE_AGENT);
          if (v0 != SENT && v1 != SENT && v2 != SENT && v3 != SENT) break;
          __builtin_amdgcn_s_sleep(1);
        }
        h_s[cur][tid + 0 * 512] = __uint_as_float(v0);
        h_s[cur][tid + 1 * 512] = __uint_as_float(v1);
        h_s[cur][tid + 2 * 512] = __uint_as_float(v2);
        h_s[cur][tid + 3 * 512] = __uint_as_float(v3);
      }

      __syncthreads();  // whole block's poll complete + stage visible

      // Safe to recycle slot (u-1)&3 now (poll success => consumers done).
      if (do_poll && tid < 128)
        __hip_atomic_store(&hring[(size_t)((u - 1) & 3) * NB * HH + wslot_off],
                           SENT, __ATOMIC_RELAXED, __HIP_MEMORY_SCOPE_AGENT);

      if (use_h) {
        float acc0 = 0.f, acc1 = 0.f, acc2 = 0.f, acc3 = 0.f;
        const float* hq = &h_s[cur][wv * 64];
#pragma unroll
        for (int k4 = 0; k4 < 16; ++k4) {
          const float w0 = wreg[4 * k4 + 0], w1 = wreg[4 * k4 + 1];
          const float w2 = wreg[4 * k4 + 2], w3 = wreg[4 * k4 + 3];
          float4 h0v = *(const float4*)(hq + 0 * HH + 4 * k4);
          float4 h1v = *(const float4*)(hq + 1 * HH + 4 * k4);
          float4 h2v = *(const float4*)(hq + 2 * HH + 4 * k4);
          float4 h3v = *(const float4*)(hq + 3 * HH + 4 * k4);
          acc0 += h0v.x * w0 + h0v.y * w1 + h0v.z * w2 + h0v.w * w3;
          acc1 += h1v.x * w0 + h1v.y * w1 + h1v.z * w2 + h1v.w * w3;
          acc2 += h2v.x * w0 + h2v.y * w1 + h2v.z * w2 + h2v.w * w3;
          acc3 += h3v.x * w0 + h3v.y * w1 + h3v.z * w2 + h3v.w * w3;
        }
        float* rp = &red[cur][((wv * 2 + gt) * 4) * 32 + d];
        rp[0 * 32] = acc0; rp[1 * 32] = acc1; rp[2 * 32] = acc2; rp[3 * 32] = acc3;
      }

      __syncthreads();  // partials visible

      if (tid < 128) {
        float zp = 0.f, op = 0.f;
        if (use_h) {
#pragma unroll
          for (int k2 = 0; k2 < 8; ++k2) {
            zp += red[cur][((k2 * 2 + 0) * 4 + bi_w) * 32 + dw];
            op += red[cur][((k2 * 2 + 1) * 4 + bi_w) * 32 + dw];
          }
        }
        const float a = zp + xpz;
        const float z = 1.f / (1.f + __expf(-a));
        const float bv = op + xpo;
        const float ab = fabsf(bv);
        const float e2 = __expf(-2.f * ab);
        const float htl = __builtin_copysignf((1.f - e2) / (1.f + e2), bv);
        const float hprev = use_h ? h_s[cur][bi_w * HH + c_base + dw] : 0.f;
        const float hn = (1.f - z) * hprev + z * htl;

        asm volatile("s_waitcnt vmcnt(0)" ::: "memory");
        __hip_atomic_store(&hring[(size_t)((u + 1) & 3) * NB * HH + wslot_off],
                           __float_as_uint(hn), __ATOMIC_RELAXED, __HIP_MEMORY_SCOPE_AGENT);
        if (ph == 0)
          text_out[((size_t)(b0 + bi_w) * TTX + t) * HH + c_base + dw] = hn;
        else if (t == T - 1)
          topic_h[(size_t)(b0 + bi_w) * HH + c_base + dw] = hn;
      }
      // no trailing barrier: 2-deep h_s/red tolerates one-phase skew
    }
  }
}

// ---------------------------------------------------------------------------
// attention: scores -> softmax weights (output) -> context  (unchanged)
// ---------------------------------------------------------------------------
__global__ __launch_bounds__(256) void sd_att(
    const float* __restrict__ text_out, const float* __restrict__ topic_h,
    const float* __restrict__ att_W, const float* __restrict__ att_b,
    float* __restrict__ context, float* __restrict__ weights_out)
{
  __shared__ alignas(16) float aw[1024];
  __shared__ float sred[256];
  __shared__ float wsh[256];
  const int b = blockIdx.x, tid = threadIdx.x;

  for (int i = tid; i < 1024; i += 256) aw[i] = att_W[i];
  __syncthreads();

  float part = 0.f;
  for (int i = tid; i < 512; i += 256) part += topic_h[(size_t)b * HH + i] * aw[512 + i];
  sred[tid] = part;
  __syncthreads();
  for (int s = 128; s > 0; s >>= 1) { if (tid < s) sred[tid] += sred[tid + s]; __syncthreads(); }
  const float cb = sred[0] + att_b[0];
  __syncthreads();

  const float* row = text_out + ((size_t)b * TTX + tid) * HH;
  float sc = cb;
  for (int d4 = 0; d4 < 128; ++d4) {
    float4 v = ((const float4*)row)[d4];
    float4 w4 = ((const float4*)aw)[d4];
    sc += v.x * w4.x + v.y * w4.y + v.z * w4.z + v.w * w4.w;
  }
  sred[tid] = sc; __syncthreads();
  for (int s = 128; s > 0; s >>= 1) { if (tid < s) sred[tid] = fmaxf(sred[tid], sred[tid + s]); __syncthreads(); }
  const float m = sred[0];
  __syncthreads();
  const float e = expf(sc - m);
  sred[tid] = e; __syncthreads();
  for (int s = 128; s > 0; s >>= 1) { if (tid < s) sred[tid] += sred[tid + s]; __syncthreads(); }
  const float wv = e / sred[0];
  wsh[tid] = wv;
  weights_out[(size_t)b * TTX + tid] = wv;
  __syncthreads();

  for (int rep = 0; rep < 2; ++rep) {
    const int dcol = rep * 256 + tid;
    float accc = 0.f;
    const float* base = text_out + (size_t)b * TTX * HH + dcol;
    for (int t2 = 0; t2 < TTX; ++t2) accc += wsh[t2] * base[(size_t)t2 * HH];
    context[(size_t)b * HH + dcol] = accc;
  }
}

// ---------------------------------------------------------------------------
// FC head: feat=[context, topic_h] -> relu(fc1) -> fc2 logits  (unchanged)
// ---------------------------------------------------------------------------
__global__ __launch_bounds__(256) void sd_fc(
    const float* __restrict__ context, const float* __restrict__ topic_h,
    const float* __restrict__ fc1_W, const float* __restrict__ fc1_b,
    const float* __restrict__ fc2_W, const float* __restrict__ fc2_b,
    float* __restrict__ logits)
{
  __shared__ alignas(16) float feat[1024];
  __shared__ float hid[512];
  const int b = blockIdx.x, tid = threadIdx.x;

  for (int i = tid; i < 512; i += 256) {
    feat[i]       = context[(size_t)b * HH + i];
    feat[512 + i] = topic_h[(size_t)b * HH + i];
  }
  __syncthreads();

  for (int rep = 0; rep < 2; ++rep) {
    const int dcol = rep * 256 + tid;
    float a = fc1_b[dcol];
#pragma unroll 4
    for (int j = 0; j < 1024; ++j) a += feat[j] * fc1_W[(size_t)j * HH + dcol];
    hid[dcol] = fmaxf(a, 0.f);
  }
  __syncthreads();

  float p0 = 0.f, p1 = 0.f, p2 = 0.f;
  for (int dv = tid; dv < 512; dv += 256) {
    const float hv = hid[dv];
    p0 += hv * fc2_W[dv * 3 + 0];
    p1 += hv * fc2_W[dv * 3 + 1];
    p2 += hv * fc2_W[dv * 3 + 2];
  }
  feat[tid] = p0; feat[256 + tid] = p1; feat[512 + tid] = p2;
  __syncthreads();
  for (int s = 128; s > 0; s >>= 1) {
    if (tid < s) {
      feat[tid] += feat[tid + s];
      feat[256 + tid] += feat[256 + tid + s];
      feat[512 + tid] += feat[512 + tid + s];
    }
    __syncthreads();
  }
  if (tid < 3) logits[b * 3 + tid] = feat[tid * 256] + fc2_b[tid];
}

// ---------------------------------------------------------------------------
extern "C" void kernel_launch(void* const* d_in, const int* in_sizes, int n_in,
                              void* d_out, int out_size, void* d_ws, size_t ws_size,
                              hipStream_t stream) {
  const int*   text  = (const int*)d_in[0];
  const int*   topic = (const int*)d_in[1];
  const float* emb   = (const float*)d_in[2];
  const float* tWz   = (const float*)d_in[3];
  const float* tbz   = (const float*)d_in[4];
  const float* tWo   = (const float*)d_in[5];
  const float* tbo   = (const float*)d_in[6];
  const float* pWz   = (const float*)d_in[7];
  const float* pbz   = (const float*)d_in[8];
  const float* pWo   = (const float*)d_in[9];
  const float* pbo   = (const float*)d_in[10];
  const float* attW  = (const float*)d_in[11];
  const float* attb  = (const float*)d_in[12];
  const float* fc1W  = (const float*)d_in[13];
  const float* fc1b  = (const float*)d_in[14];
  const float* fc2W  = (const float*)d_in[15];
  const float* fc2b  = (const float*)d_in[16];

  float* out = (float*)d_out;            // [0,192): logits, [192,+16384): weights
  float* ws  = (float*)d_ws;

  float* xp_text  = ws;                                    // 256*64*1024
  float* xp_topic = xp_text + (size_t)TTX * 64 * 1024;     // 16*64*1024
  float* text_o   = xp_topic + (size_t)TTP * 64 * 1024;    // 64*256*512
  float* topic_hv = text_o + (size_t)NB * TTX * HH;        // 64*512
  float* ctx      = topic_hv + (size_t)NB * HH;            // 64*512
  unsigned* hring = (unsigned*)(ctx + (size_t)NB * HH);    // 4*64*512 u32

  // bf16 B_T buffers live in the text_o region: prep+xproj finish before
  // sd_recur starts writing text_o (stream-serial), so the overlap is safe.
  unsigned short* bt_text  = (unsigned short*)text_o;      // 1024*320 bf16
  unsigned short* bt_topic = bt_text + 1024 * 320;         // 1024*320 bf16

  sd_init_ring<<<dim3(4 * NB * HH / 256), dim3(256), 0, stream>>>(hring);
  sd_prep_bt<<<dim3(1280), dim3(256), 0, stream>>>(tWz, tWo, bt_text);
  sd_prep_bt<<<dim3(1280), dim3(256), 0, stream>>>(pWz, pWo, bt_topic);
  sd_xproj_mfma<<<dim3(TTX, 4), dim3(256), 0, stream>>>(text, TTX, emb, bt_text, tbz, tbo, xp_text);
  sd_xproj_mfma<<<dim3(TTP, 4), dim3(256), 0, stream>>>(topic, TTP, emb, bt_topic, pbz, pbo, xp_topic);
  sd_recur<<<dim3(256), dim3(512), 0, stream>>>(tWz, tWo, pWz, pWo, xp_text, xp_topic,
                                                text_o, hring, topic_hv);
  sd_att<<<dim3(64), dim3(256), 0, stream>>>(text_o, topic_hv, attW, attb, ctx, out + 192);
  sd_fc<<<dim3(64), dim3(256), 0, stream>>>(ctx, topic_hv, fc1W, fc1b, fc2W, fc2b, out);
}

// Round 8
// 670.945 us; speedup vs baseline: 1.9588x; 1.2920x over previous
//
#include <hip/hip_runtime.h>
#include <math.h>

#define NB 64      // batch
#define TTX 256    // text timesteps
#define TTP 16     // topic timesteps
#define EE 300     // embedding dim
#define HH 512     // hidden
#define SENT 0x7FC0DEADu   // NaN-payload sentinel; real h can never be NaN

typedef __attribute__((ext_vector_type(4))) float f32x4;
typedef __attribute__((ext_vector_type(8))) short short8;

__device__ __forceinline__ unsigned short bf16cvt(float f) {
  unsigned u = __float_as_uint(f);
  u += 0x7FFFu + ((u >> 16) & 1u);   // RNE
  return (unsigned short)(u >> 16);
}
__device__ __forceinline__ unsigned short bf16cvt_bits(unsigned u) {
  u += 0x7FFFu + ((u >> 16) & 1u);   // RNE
  return (unsigned short)(u >> 16);
}

// ---------------------------------------------------------------------------
// init: poison all 4 h-ring slots (every call: graph replays deterministic)
// ---------------------------------------------------------------------------
__global__ void sd_init_ring(unsigned* __restrict__ hring) {
  hring[blockIdx.x * blockDim.x + threadIdx.x] = SENT;  // grid == 4*NB*HH
}

// ---------------------------------------------------------------------------
// prep: B_T[c][k] bf16, c in [0,1024), k in [0,320) zero-padded (unchanged)
// ---------------------------------------------------------------------------
__global__ __launch_bounds__(256) void sd_prep_bt(
    const float* __restrict__ Wz, const float* __restrict__ Wo,
    unsigned short* __restrict__ Bt)
{
  const int i = blockIdx.x * blockDim.x + threadIdx.x;  // [0, 1024*320)
  const int k = i % 320;
  const int c = i / 320;
  const float* W = (c < 512) ? Wz : Wo;
  const float v = (k < 300) ? W[(size_t)k * HH + (c & 511)] : 0.f;
  Bt[i] = bf16cvt(v);
}

// ---------------------------------------------------------------------------
// xproj via MFMA bf16 (unchanged from round 7 — verified passing)
// ---------------------------------------------------------------------------
__global__ __launch_bounds__(256) void sd_xproj_mfma(
    const int* __restrict__ idx, int T,
    const float* __restrict__ emb,
    const unsigned short* __restrict__ Bt,
    const float* __restrict__ bz, const float* __restrict__ bo,
    float* __restrict__ xp)
{
  __shared__ alignas(16) unsigned short Als[64 * 328];
  __shared__ int tok[64];

  const int tid = threadIdx.x;
  const int t   = blockIdx.x;
  const int c0  = blockIdx.y * 256;

  if (tid < 64) tok[tid] = idx[tid * T + t];
  __syncthreads();

  {
    const int m  = tid >> 2;
    const int qt = tid & 3;
    const float* er = emb + (size_t)tok[m] * EE;
    unsigned short* ar = Als + m * 328;
    for (int j = qt; j < 75; j += 4) {
      const float4 v = *(const float4*)(er + 4 * j);
      ushort4 o;
      o.x = bf16cvt(v.x); o.y = bf16cvt(v.y);
      o.z = bf16cvt(v.z); o.w = bf16cvt(v.w);
      *(ushort4*)(ar + 4 * j) = o;
    }
    if (qt == 0) {
      for (int k = 300; k < 328; ++k) ar[k] = 0;
    }
  }
  __syncthreads();

  const int w  = tid >> 6;
  const int l  = tid & 63;
  const int lr = l & 15;
  const int lg = l >> 4;

  f32x4 acc[4][4];
#pragma unroll
  for (int ms = 0; ms < 4; ++ms)
#pragma unroll
    for (int ns = 0; ns < 4; ++ns)
      acc[ms][ns] = (f32x4){0.f, 0.f, 0.f, 0.f};

  const unsigned short* bbase = Bt + ((size_t)(c0 + w * 64 + lr)) * 320 + 8 * lg;

#pragma unroll 2
  for (int kc = 0; kc < 10; ++kc) {
    short8 bfr[4];
#pragma unroll
    for (int ns = 0; ns < 4; ++ns)
      bfr[ns] = *reinterpret_cast<const short8*>(bbase + (size_t)ns * 16 * 320 + kc * 32);
    short8 afr[4];
#pragma unroll
    for (int ms = 0; ms < 4; ++ms)
      afr[ms] = *reinterpret_cast<const short8*>(Als + (ms * 16 + lr) * 328 + kc * 32 + 8 * lg);
#pragma unroll
    for (int ms = 0; ms < 4; ++ms)
#pragma unroll
      for (int ns = 0; ns < 4; ++ns)
        acc[ms][ns] = __builtin_amdgcn_mfma_f32_16x16x32_bf16(afr[ms], bfr[ns], acc[ms][ns], 0, 0, 0);
  }

#pragma unroll
  for (int ns = 0; ns < 4; ++ns) {
    const int cg = c0 + w * 64 + ns * 16 + lr;
    const float bias = (cg < 512) ? bz[cg] : bo[cg - 512];
#pragma unroll
    for (int ms = 0; ms < 4; ++ms) {
#pragma unroll
      for (int r = 0; r < 4; ++r) {
        const int row = ms * 16 + lg * 4 + r;
        xp[((size_t)t * 64 + row) * 1024 + cg] = acc[ms][ns][r] + bias;
      }
    }
  }
}

// ---------------------------------------------------------------------------
// Persistent recurrence kernel — round-4 skeleton (512 thr = 8 waves,
// block-wide sentinel poll, 2 syncs/step, vmcnt(0) — all proven at 680us),
// with the matvec phase replaced by bf16 MFMA (round-7-verified recipe).
//
//   Per block matvec: [4 rows x 512 k] x [512 k x 64 cols(2gt x 32d)].
//   One 16x16 M-tile (rows 4..15 padded: lanes with (l&15)>3 read row l&3
//   duplicates; their D rows are discarded). 4 N-subtiles; K split 8 ways
//   across waves (64 k each = 2 MFMA k-chunks). Fragments per round-7:
//   A row = lane&15, B col = lane&15, k-slot = 8*(lane>>4)+e consistent on
//   both operands; C/D col = lane&15, row = (lane>>4)*4 + reg (m89).
//   Wave wv writes its real C rows (lanes 0..15, regs 0..3) to red[wv];
//   writers reduce over 8 waves exactly as the old FMA path did.
//
//   h is staged BOTH as fp32 (h_s, unchanged — writers' hprev stays exact)
//   and bf16 (h_bf, row stride 520 to spread banks) during the poll-stage.
//   Only the sum(w*h) terms see bf16 rounding: error ~3e-4 per gate
//   pre-activation, contractive recurrence => final absmax ~1e-3 < 2.1e-3.
//
//   Ring protocol byte-identical to rounds 4/7 (proofs carry over).
// ---------------------------------------------------------------------------
__global__ __launch_bounds__(512) void sd_recur(
    const float* __restrict__ tWz, const float* __restrict__ tWo,
    const float* __restrict__ pWz, const float* __restrict__ pWo,
    const float* __restrict__ xp_text, const float* __restrict__ xp_topic,
    float* __restrict__ text_out, unsigned* __restrict__ hring,
    float* __restrict__ topic_h)
{
  __shared__ alignas(16) float h_s[2][4 * HH];          // fp32 staged h (dbuf)
  __shared__ alignas(16) unsigned short h_bf[2][2080];  // bf16 h, [4 rows][520]
  __shared__ alignas(16) float red[2][2048];            // [8 wv][4 row][64 col]

  const int tid = threadIdx.x;
  const int bid = blockIdx.x;
  const int x = bid & 7;           // XCD (heuristic placement)
  const int q = bid >> 3;
  const int g = x + 8 * (q >> 4);  // batch group 0..15
  const int slice = q & 15;        // dim slice 0..15
  const int b0 = g * 4;
  const int c_base = slice * 32;

  const int wv = tid >> 6;         // wave id = k-eighth (0..7)
  const int lane = tid & 63;
  const int lg = lane >> 4;        // k-slot group 0..3
  const int l15 = lane & 15;

  const int bi_w = tid >> 5;       // writer mapping (tid<128): batch row 0..3
  const int dw = tid & 31;

  const size_t wslot_off = (size_t)(b0 + bi_w) * HH + c_base + dw;

  int u = 0;  // global step counter across both phases

  for (int ph = 0; ph < 2; ++ph) {
    const float* Wz = ph ? pWz : tWz;
    const float* Wo = ph ? pWo : tWo;
    const float* xp = ph ? xp_topic : xp_text;
    const int T = ph ? TTP : TTX;

    // --- prep W h-part bf16 B-fragments (once per phase) ----------------
    // wfrag[ns][kc]: 8 bf16 for k = wv*64 + kc*32 + 8*lg + e,
    //                col c = ns*16 + l15 (gate = c>>5, dim = c&31)
    short8 wfrag[4][2];
#pragma unroll
    for (int ns = 0; ns < 4; ++ns) {
      const float* Wg = (ns < 2) ? Wz : Wo;
      const int dim = (ns & 1) * 16 + l15;
#pragma unroll
      for (int kc = 0; kc < 2; ++kc) {
        const int kb = wv * 64 + kc * 32 + 8 * lg;
        short8 f;
#pragma unroll
        for (int e = 0; e < 8; ++e)
          f[e] = (short)bf16cvt(Wg[(size_t)(EE + kb + e) * HH + c_base + dim]);
        wfrag[ns][kc] = f;
      }
    }

    for (int t = 0; t < T; ++t, ++u) {
      const int cur = u & 1;
      const bool do_poll = (u > 0);
      const bool use_h   = (t > 0);

      float xpz = 0.f, xpo = 0.f;
      if (tid < 128) {
        const float* xpr = xp + ((size_t)t * 64 + (b0 + bi_w)) * 1024 + c_base + dw;
        xpz = xpr[0];
        xpo = xpr[512];
      }

      if (do_poll) {
        // block-wide poll-stage (round-4 pattern): word tid+j*512 = row j, col tid
        const unsigned* src = hring + (size_t)(u & 3) * NB * HH + (size_t)b0 * HH;
        unsigned v0, v1, v2, v3;
        for (;;) {
          v0 = __hip_atomic_load(&src[tid + 0 * 512], __ATOMIC_RELAXED, __HIP_MEMORY_SCOPE_AGENT);
          v1 = __hip_atomic_load(&src[tid + 1 * 512], __ATOMIC_RELAXED, __HIP_MEMORY_SCOPE_AGENT);
          v2 = __hip_atomic_load(&src[tid + 2 * 512], __ATOMIC_RELAXED, __HIP_MEMORY_SCOPE_AGENT);
          v3 = __hip_atomic_load(&src[tid + 3 * 512], __ATOMIC_RELAXED, __HIP_MEMORY_SCOPE_AGENT);
          if (v0 != SENT && v1 != SENT && v2 != SENT && v3 != SENT) break;
          __builtin_amdgcn_s_sleep(1);
        }
        h_s[cur][tid + 0 * 512] = __uint_as_float(v0);
        h_s[cur][tid + 1 * 512] = __uint_as_float(v1);
        h_s[cur][tid + 2 * 512] = __uint_as_float(v2);
        h_s[cur][tid + 3 * 512] = __uint_as_float(v3);
        // bf16 copy for MFMA A-operand (row stride 520)
        h_bf[cur][0 * 520 + tid] = bf16cvt_bits(v0);
        h_bf[cur][1 * 520 + tid] = bf16cvt_bits(v1);
        h_bf[cur][2 * 520 + tid] = bf16cvt_bits(v2);
        h_bf[cur][3 * 520 + tid] = bf16cvt_bits(v3);
      }

      __syncthreads();  // whole block's poll complete + stages visible

      // Safe to recycle slot (u-1)&3 now (poll success => consumers done).
      if (do_poll && tid < 128)
        __hip_atomic_store(&hring[(size_t)((u - 1) & 3) * NB * HH + wslot_off],
                           SENT, __ATOMIC_RELAXED, __HIP_MEMORY_SCOPE_AGENT);

      if (use_h) {
        // A-frags: row (l&15)&3 = lane&3 (rows 4..15 are duplicates, D rows
        // discarded); k = wv*64 + kc*32 + 8*lg + e
        const unsigned short* hb = &h_bf[cur][(lane & 3) * 520 + wv * 64 + 8 * lg];
        const short8 a0 = *reinterpret_cast<const short8*>(hb + 0);
        const short8 a1 = *reinterpret_cast<const short8*>(hb + 32);

        f32x4 acc[4];
#pragma unroll
        for (int ns = 0; ns < 4; ++ns) {
          acc[ns] = (f32x4){0.f, 0.f, 0.f, 0.f};
          acc[ns] = __builtin_amdgcn_mfma_f32_16x16x32_bf16(a0, wfrag[ns][0], acc[ns], 0, 0, 0);
          acc[ns] = __builtin_amdgcn_mfma_f32_16x16x32_bf16(a1, wfrag[ns][1], acc[ns], 0, 0, 0);
        }
        // real C rows live in lanes 0..15 (row = reg), col = ns*16 + lane
        if (lane < 16) {
#pragma unroll
          for (int ns = 0; ns < 4; ++ns)
#pragma unroll
            for (int r = 0; r < 4; ++r)
              red[cur][wv * 256 + r * 64 + ns * 16 + lane] = acc[ns][r];
        }
      }

      __syncthreads();  // partials visible

      if (tid < 128) {
        float zp = 0.f, op = 0.f;
        if (use_h) {
#pragma unroll
          for (int k2 = 0; k2 < 8; ++k2) {
            zp += red[cur][k2 * 256 + bi_w * 64 + dw];        // gate z: col dw
            op += red[cur][k2 * 256 + bi_w * 64 + 32 + dw];   // gate o: col 32+dw
          }
        }
        const float a = zp + xpz;
        const float z = 1.f / (1.f + __expf(-a));
        const float bv = op + xpo;
        const float ab = fabsf(bv);
        const float e2 = __expf(-2.f * ab);
        const float htl = __builtin_copysignf((1.f - e2) / (1.f + e2), bv);
        const float hprev = use_h ? h_s[cur][bi_w * HH + c_base + dw] : 0.f;
        const float hn = (1.f - z) * hprev + z * htl;

        asm volatile("s_waitcnt vmcnt(0)" ::: "memory");
        __hip_atomic_store(&hring[(size_t)((u + 1) & 3) * NB * HH + wslot_off],
                           __float_as_uint(hn), __ATOMIC_RELAXED, __HIP_MEMORY_SCOPE_AGENT);
        if (ph == 0)
          text_out[((size_t)(b0 + bi_w) * TTX + t) * HH + c_base + dw] = hn;
        else if (t == T - 1)
          topic_h[(size_t)(b0 + bi_w) * HH + c_base + dw] = hn;
      }
      // no trailing barrier: 2-deep buffers tolerate one-phase skew
    }
  }
}

// ---------------------------------------------------------------------------
// attention: scores -> softmax weights (output) -> context  (unchanged)
// ---------------------------------------------------------------------------
__global__ __launch_bounds__(256) void sd_att(
    const float* __restrict__ text_out, const float* __restrict__ topic_h,
    const float* __restrict__ att_W, const float* __restrict__ att_b,
    float* __restrict__ context, float* __restrict__ weights_out)
{
  __shared__ alignas(16) float aw[1024];
  __shared__ float sred[256];
  __shared__ float wsh[256];
  const int b = blockIdx.x, tid = threadIdx.x;

  for (int i = tid; i < 1024; i += 256) aw[i] = att_W[i];
  __syncthreads();

  float part = 0.f;
  for (int i = tid; i < 512; i += 256) part += topic_h[(size_t)b * HH + i] * aw[512 + i];
  sred[tid] = part;
  __syncthreads();
  for (int s = 128; s > 0; s >>= 1) { if (tid < s) sred[tid] += sred[tid + s]; __syncthreads(); }
  const float cb = sred[0] + att_b[0];
  __syncthreads();

  const float* row = text_out + ((size_t)b * TTX + tid) * HH;
  float sc = cb;
  for (int d4 = 0; d4 < 128; ++d4) {
    float4 v = ((const float4*)row)[d4];
    float4 w4 = ((const float4*)aw)[d4];
    sc += v.x * w4.x + v.y * w4.y + v.z * w4.z + v.w * w4.w;
  }
  sred[tid] = sc; __syncthreads();
  for (int s = 128; s > 0; s >>= 1) { if (tid < s) sred[tid] = fmaxf(sred[tid], sred[tid + s]); __syncthreads(); }
  const float m = sred[0];
  __syncthreads();
  const float e = expf(sc - m);
  sred[tid] = e; __syncthreads();
  for (int s = 128; s > 0; s >>= 1) { if (tid < s) sred[tid] += sred[tid + s]; __syncthreads(); }
  const float wv = e / sred[0];
  wsh[tid] = wv;
  weights_out[(size_t)b * TTX + tid] = wv;
  __syncthreads();

  for (int rep = 0; rep < 2; ++rep) {
    const int dcol = rep * 256 + tid;
    float accc = 0.f;
    const float* base = text_out + (size_t)b * TTX * HH + dcol;
    for (int t2 = 0; t2 < TTX; ++t2) accc += wsh[t2] * base[(size_t)t2 * HH];
    context[(size_t)b * HH + dcol] = accc;
  }
}

// ---------------------------------------------------------------------------
// FC head: feat=[context, topic_h] -> relu(fc1) -> fc2 logits  (unchanged)
// ---------------------------------------------------------------------------
__global__ __launch_bounds__(256) void sd_fc(
    const float* __restrict__ context, const float* __restrict__ topic_h,
    const float* __restrict__ fc1_W, const float* __restrict__ fc1_b,
    const float* __restrict__ fc2_W, const float* __restrict__ fc2_b,
    float* __restrict__ logits)
{
  __shared__ alignas(16) float feat[1024];
  __shared__ float hid[512];
  const int b = blockIdx.x, tid = threadIdx.x;

  for (int i = tid; i < 512; i += 256) {
    feat[i]       = context[(size_t)b * HH + i];
    feat[512 + i] = topic_h[(size_t)b * HH + i];
  }
  __syncthreads();

  for (int rep = 0; rep < 2; ++rep) {
    const int dcol = rep * 256 + tid;
    float a = fc1_b[dcol];
#pragma unroll 4
    for (int j = 0; j < 1024; ++j) a += feat[j] * fc1_W[(size_t)j * HH + dcol];
    hid[dcol] = fmaxf(a, 0.f);
  }
  __syncthreads();

  float p0 = 0.f, p1 = 0.f, p2 = 0.f;
  for (int dv = tid; dv < 512; dv += 256) {
    const float hv = hid[dv];
    p0 += hv * fc2_W[dv * 3 + 0];
    p1 += hv * fc2_W[dv * 3 + 1];
    p2 += hv * fc2_W[dv * 3 + 2];
  }
  feat[tid] = p0; feat[256 + tid] = p1; feat[512 + tid] = p2;
  __syncthreads();
  for (int s = 128; s > 0; s >>= 1) {
    if (tid < s) {
      feat[tid] += feat[tid + s];
      feat[256 + tid] += feat[256 + tid + s];
      feat[512 + tid] += feat[512 + tid + s];
    }
    __syncthreads();
  }
  if (tid < 3) logits[b * 3 + tid] = feat[tid * 256] + fc2_b[tid];
}

// ---------------------------------------------------------------------------
extern "C" void kernel_launch(void* const* d_in, const int* in_sizes, int n_in,
                              void* d_out, int out_size, void* d_ws, size_t ws_size,
                              hipStream_t stream) {
  const int*   text  = (const int*)d_in[0];
  const int*   topic = (const int*)d_in[1];
  const float* emb   = (const float*)d_in[2];
  const float* tWz   = (const float*)d_in[3];
  const float* tbz   = (const float*)d_in[4];
  const float* tWo   = (const float*)d_in[5];
  const float* tbo   = (const float*)d_in[6];
  const float* pWz   = (const float*)d_in[7];
  const float* pbz   = (const float*)d_in[8];
  const float* pWo   = (const float*)d_in[9];
  const float* pbo   = (const float*)d_in[10];
  const float* attW  = (const float*)d_in[11];
  const float* attb  = (const float*)d_in[12];
  const float* fc1W  = (const float*)d_in[13];
  const float* fc1b  = (const float*)d_in[14];
  const float* fc2W  = (const float*)d_in[15];
  const float* fc2b  = (const float*)d_in[16];

  float* out = (float*)d_out;            // [0,192): logits, [192,+16384): weights
  float* ws  = (float*)d_ws;

  float* xp_text  = ws;                                    // 256*64*1024
  float* xp_topic = xp_text + (size_t)TTX * 64 * 1024;     // 16*64*1024
  float* text_o   = xp_topic + (size_t)TTP * 64 * 1024;    // 64*256*512
  float* topic_hv = text_o + (size_t)NB * TTX * HH;        // 64*512
  float* ctx      = topic_hv + (size_t)NB * HH;            // 64*512
  unsigned* hring = (unsigned*)(ctx + (size_t)NB * HH);    // 4*64*512 u32

  // bf16 B_T buffers live in the text_o region: prep+xproj finish before
  // sd_recur starts writing text_o (stream-serial), so the overlap is safe.
  unsigned short* bt_text  = (unsigned short*)text_o;      // 1024*320 bf16
  unsigned short* bt_topic = bt_text + 1024 * 320;         // 1024*320 bf16

  sd_init_ring<<<dim3(4 * NB * HH / 256), dim3(256), 0, stream>>>(hring);
  sd_prep_bt<<<dim3(1280), dim3(256), 0, stream>>>(tWz, tWo, bt_text);
  sd_prep_bt<<<dim3(1280), dim3(256), 0, stream>>>(pWz, pWo, bt_topic);
  sd_xproj_mfma<<<dim3(TTX, 4), dim3(256), 0, stream>>>(text, TTX, emb, bt_text, tbz, tbo, xp_text);
  sd_xproj_mfma<<<dim3(TTP, 4), dim3(256), 0, stream>>>(topic, TTP, emb, bt_topic, pbz, pbo, xp_topic);
  sd_recur<<<dim3(256), dim3(512), 0, stream>>>(tWz, tWo, pWz, pWo, xp_text, xp_topic,
                                                text_o, hring, topic_hv);
  sd_att<<<dim3(64), dim3(256), 0, stream>>>(text_o, topic_hv, attW, attb, ctx, out + 192);
  sd_fc<<<dim3(64), dim3(256), 0, stream>>>(ctx, topic_hv, fc1W, fc1b, fc2W, fc2b, out);
}

// Round 9
// 666.257 us; speedup vs baseline: 1.9726x; 1.0070x over previous
//
#include <hip/hip_runtime.h>
#include <math.h>

#define NB 64      // batch
#define TTX 256    // text timesteps
#define TTP 16     // topic timesteps
#define EE 300     // embedding dim
#define HH 512     // hidden
#define SENT 0x7FC0DEADu   // NaN-payload sentinel; real h can never be NaN

typedef __attribute__((ext_vector_type(4))) float f32x4;
typedef __attribute__((ext_vector_type(8))) short short8;

__device__ __forceinline__ unsigned short bf16cvt(float f) {
  unsigned u = __float_as_uint(f);
  u += 0x7FFFu + ((u >> 16) & 1u);   // RNE
  return (unsigned short)(u >> 16);
}
__device__ __forceinline__ unsigned short bf16cvt_bits(unsigned u) {
  u += 0x7FFFu + ((u >> 16) & 1u);   // RNE
  return (unsigned short)(u >> 16);
}

// ---------------------------------------------------------------------------
// init: poison all 4 h-ring slots (every call: graph replays deterministic)
// ---------------------------------------------------------------------------
__global__ void sd_init_ring(unsigned* __restrict__ hring) {
  hring[blockIdx.x * blockDim.x + threadIdx.x] = SENT;  // grid == 4*NB*HH
}

// ---------------------------------------------------------------------------
// prep (merged): Bt[0..1024*320) = text weights, [1024*320..2*1024*320) =
// topic weights. B_T[c][k] bf16, c in [0,1024), k zero-padded >= 300.
// ---------------------------------------------------------------------------
__global__ __launch_bounds__(256) void sd_prep_bt(
    const float* __restrict__ tWz, const float* __restrict__ tWo,
    const float* __restrict__ pWz, const float* __restrict__ pWo,
    unsigned short* __restrict__ Bt)
{
  const int i = blockIdx.x * blockDim.x + threadIdx.x;  // [0, 2*1024*320)
  const int half = 1024 * 320;
  const int j = (i < half) ? i : i - half;
  const int k = j % 320;
  const int c = j / 320;
  const float* W = (i < half) ? ((c < 512) ? tWz : tWo) : ((c < 512) ? pWz : pWo);
  const float v = (k < 300) ? W[(size_t)k * HH + (c & 511)] : 0.f;
  Bt[i] = bf16cvt(v);
}

// ---------------------------------------------------------------------------
// xproj via MFMA bf16 (merged text+topic; body identical to round-7-verified)
// ---------------------------------------------------------------------------
__global__ __launch_bounds__(256) void sd_xproj_mfma(
    const int* __restrict__ text_idx, const int* __restrict__ topic_idx,
    const float* __restrict__ emb,
    const unsigned short* __restrict__ bt_text, const unsigned short* __restrict__ bt_topic,
    const float* __restrict__ tbz, const float* __restrict__ tbo,
    const float* __restrict__ pbz, const float* __restrict__ pbo,
    float* __restrict__ xp_text, float* __restrict__ xp_topic)
{
  __shared__ alignas(16) unsigned short Als[64 * 328];
  __shared__ int tok[64];

  const bool is_text = blockIdx.x < TTX;
  const int t   = is_text ? blockIdx.x : blockIdx.x - TTX;
  const int T   = is_text ? TTX : TTP;
  const int* idx = is_text ? text_idx : topic_idx;
  const unsigned short* Bt = is_text ? bt_text : bt_topic;
  const float* bz = is_text ? tbz : pbz;
  const float* bo = is_text ? tbo : pbo;
  float* xp = is_text ? xp_text : xp_topic;

  const int tid = threadIdx.x;
  const int c0  = blockIdx.y * 256;

  if (tid < 64) tok[tid] = idx[tid * T + t];
  __syncthreads();

  {
    const int m  = tid >> 2;
    const int qt = tid & 3;
    const float* er = emb + (size_t)tok[m] * EE;
    unsigned short* ar = Als + m * 328;
    for (int j = qt; j < 75; j += 4) {
      const float4 v = *(const float4*)(er + 4 * j);
      ushort4 o;
      o.x = bf16cvt(v.x); o.y = bf16cvt(v.y);
      o.z = bf16cvt(v.z); o.w = bf16cvt(v.w);
      *(ushort4*)(ar + 4 * j) = o;
    }
    if (qt == 0) {
      for (int k = 300; k < 328; ++k) ar[k] = 0;
    }
  }
  __syncthreads();

  const int w  = tid >> 6;
  const int l  = tid & 63;
  const int lr = l & 15;
  const int lg = l >> 4;

  f32x4 acc[4][4];
#pragma unroll
  for (int ms = 0; ms < 4; ++ms)
#pragma unroll
    for (int ns = 0; ns < 4; ++ns)
      acc[ms][ns] = (f32x4){0.f, 0.f, 0.f, 0.f};

  const unsigned short* bbase = Bt + ((size_t)(c0 + w * 64 + lr)) * 320 + 8 * lg;

#pragma unroll 2
  for (int kc = 0; kc < 10; ++kc) {
    short8 bfr[4];
#pragma unroll
    for (int ns = 0; ns < 4; ++ns)
      bfr[ns] = *reinterpret_cast<const short8*>(bbase + (size_t)ns * 16 * 320 + kc * 32);
    short8 afr[4];
#pragma unroll
    for (int ms = 0; ms < 4; ++ms)
      afr[ms] = *reinterpret_cast<const short8*>(Als + (ms * 16 + lr) * 328 + kc * 32 + 8 * lg);
#pragma unroll
    for (int ms = 0; ms < 4; ++ms)
#pragma unroll
      for (int ns = 0; ns < 4; ++ns)
        acc[ms][ns] = __builtin_amdgcn_mfma_f32_16x16x32_bf16(afr[ms], bfr[ns], acc[ms][ns], 0, 0, 0);
  }

#pragma unroll
  for (int ns = 0; ns < 4; ++ns) {
    const int cg = c0 + w * 64 + ns * 16 + lr;
    const float bias = (cg < 512) ? bz[cg] : bo[cg - 512];
#pragma unroll
    for (int ms = 0; ms < 4; ++ms) {
#pragma unroll
      for (int r = 0; r < 4; ++r) {
        const int row = ms * 16 + lg * 4 + r;
        xp[((size_t)t * 64 + row) * 1024 + cg] = acc[ms][ns][r] + bias;
      }
    }
  }
}

// ---------------------------------------------------------------------------
// Persistent recurrence kernel — round-8 structure (453us verified) with ONE
// isolated change: vmcnt(0) -> vmcnt(1) before the real h-store.
//   Safety: vmcnt retires in issue order. vmcnt(1) leaves at most the most
//   recently issued vmem op in flight = this step's poison (slot (u-1)&3,
//   DIFFERENT address than the h-store's slot (u+1)&3). The step-(u-2)
//   poison of slot (u+1)&3 (same address) is strictly older => retired at
//   the coherence point before the real store issues; MALL same-address
//   order does the rest. Consumer-side: block C polling slot s=(u-1)&3 at
//   step u+3 has already observed h(u+2) from its producers, whose stores
//   were issued after their step-u+1 vmcnt(1) drained their step-u poisons
//   => the poison of slot s reached the coherence point before C's poll.
// ---------------------------------------------------------------------------
__global__ __launch_bounds__(512) void sd_recur(
    const float* __restrict__ tWz, const float* __restrict__ tWo,
    const float* __restrict__ pWz, const float* __restrict__ pWo,
    const float* __restrict__ xp_text, const float* __restrict__ xp_topic,
    float* __restrict__ text_out, unsigned* __restrict__ hring,
    float* __restrict__ topic_h)
{
  __shared__ alignas(16) float h_s[2][4 * HH];          // fp32 staged h (dbuf)
  __shared__ alignas(16) unsigned short h_bf[2][2080];  // bf16 h, [4 rows][520]
  __shared__ alignas(16) float red[2][2048];            // [8 wv][4 row][64 col]

  const int tid = threadIdx.x;
  const int bid = blockIdx.x;
  const int x = bid & 7;           // XCD (heuristic placement)
  const int q = bid >> 3;
  const int g = x + 8 * (q >> 4);  // batch group 0..15
  const int slice = q & 15;        // dim slice 0..15
  const int b0 = g * 4;
  const int c_base = slice * 32;

  const int wv = tid >> 6;         // wave id = k-eighth (0..7)
  const int lane = tid & 63;
  const int lg = lane >> 4;        // k-slot group 0..3
  const int l15 = lane & 15;

  const int bi_w = tid >> 5;       // writer mapping (tid<128): batch row 0..3
  const int dw = tid & 31;

  const size_t wslot_off = (size_t)(b0 + bi_w) * HH + c_base + dw;

  int u = 0;  // global step counter across both phases

  for (int ph = 0; ph < 2; ++ph) {
    const float* Wz = ph ? pWz : tWz;
    const float* Wo = ph ? pWo : tWo;
    const float* xp = ph ? xp_topic : xp_text;
    const int T = ph ? TTP : TTX;

    // --- prep W h-part bf16 B-fragments (once per phase) ----------------
    short8 wfrag[4][2];
#pragma unroll
    for (int ns = 0; ns < 4; ++ns) {
      const float* Wg = (ns < 2) ? Wz : Wo;
      const int dim = (ns & 1) * 16 + l15;
#pragma unroll
      for (int kc = 0; kc < 2; ++kc) {
        const int kb = wv * 64 + kc * 32 + 8 * lg;
        short8 f;
#pragma unroll
        for (int e = 0; e < 8; ++e)
          f[e] = (short)bf16cvt(Wg[(size_t)(EE + kb + e) * HH + c_base + dim]);
        wfrag[ns][kc] = f;
      }
    }

    for (int t = 0; t < T; ++t, ++u) {
      const int cur = u & 1;
      const bool do_poll = (u > 0);
      const bool use_h   = (t > 0);

      float xpz = 0.f, xpo = 0.f;
      if (tid < 128) {
        const float* xpr = xp + ((size_t)t * 64 + (b0 + bi_w)) * 1024 + c_base + dw;
        xpz = xpr[0];
        xpo = xpr[512];
      }

      if (do_poll) {
        // block-wide poll-stage: word tid+j*512 = row j, col tid
        const unsigned* src = hring + (size_t)(u & 3) * NB * HH + (size_t)b0 * HH;
        unsigned v0, v1, v2, v3;
        for (;;) {
          v0 = __hip_atomic_load(&src[tid + 0 * 512], __ATOMIC_RELAXED, __HIP_MEMORY_SCOPE_AGENT);
          v1 = __hip_atomic_load(&src[tid + 1 * 512], __ATOMIC_RELAXED, __HIP_MEMORY_SCOPE_AGENT);
          v2 = __hip_atomic_load(&src[tid + 2 * 512], __ATOMIC_RELAXED, __HIP_MEMORY_SCOPE_AGENT);
          v3 = __hip_atomic_load(&src[tid + 3 * 512], __ATOMIC_RELAXED, __HIP_MEMORY_SCOPE_AGENT);
          if (v0 != SENT && v1 != SENT && v2 != SENT && v3 != SENT) break;
          __builtin_amdgcn_s_sleep(1);
        }
        h_s[cur][tid + 0 * 512] = __uint_as_float(v0);
        h_s[cur][tid + 1 * 512] = __uint_as_float(v1);
        h_s[cur][tid + 2 * 512] = __uint_as_float(v2);
        h_s[cur][tid + 3 * 512] = __uint_as_float(v3);
        h_bf[cur][0 * 520 + tid] = bf16cvt_bits(v0);
        h_bf[cur][1 * 520 + tid] = bf16cvt_bits(v1);
        h_bf[cur][2 * 520 + tid] = bf16cvt_bits(v2);
        h_bf[cur][3 * 520 + tid] = bf16cvt_bits(v3);
      }

      __syncthreads();  // whole block's poll complete + stages visible

      // Safe to recycle slot (u-1)&3 now (poll success => consumers done).
      if (do_poll && tid < 128)
        __hip_atomic_store(&hring[(size_t)((u - 1) & 3) * NB * HH + wslot_off],
                           SENT, __ATOMIC_RELAXED, __HIP_MEMORY_SCOPE_AGENT);

      if (use_h) {
        const unsigned short* hb = &h_bf[cur][(lane & 3) * 520 + wv * 64 + 8 * lg];
        const short8 a0 = *reinterpret_cast<const short8*>(hb + 0);
        const short8 a1 = *reinterpret_cast<const short8*>(hb + 32);

        f32x4 acc[4];
#pragma unroll
        for (int ns = 0; ns < 4; ++ns) {
          acc[ns] = (f32x4){0.f, 0.f, 0.f, 0.f};
          acc[ns] = __builtin_amdgcn_mfma_f32_16x16x32_bf16(a0, wfrag[ns][0], acc[ns], 0, 0, 0);
          acc[ns] = __builtin_amdgcn_mfma_f32_16x16x32_bf16(a1, wfrag[ns][1], acc[ns], 0, 0, 0);
        }
        if (lane < 16) {
#pragma unroll
          for (int ns = 0; ns < 4; ++ns)
#pragma unroll
            for (int r = 0; r < 4; ++r)
              red[cur][wv * 256 + r * 64 + ns * 16 + lane] = acc[ns][r];
        }
      }

      __syncthreads();  // partials visible

      if (tid < 128) {
        float zp = 0.f, op = 0.f;
        if (use_h) {
#pragma unroll
          for (int k2 = 0; k2 < 8; ++k2) {
            zp += red[cur][k2 * 256 + bi_w * 64 + dw];        // gate z
            op += red[cur][k2 * 256 + bi_w * 64 + 32 + dw];   // gate o
          }
        }
        const float a = zp + xpz;
        const float z = 1.f / (1.f + __expf(-a));
        const float bv = op + xpo;
        const float ab = fabsf(bv);
        const float e2 = __expf(-2.f * ab);
        const float htl = __builtin_copysignf((1.f - e2) / (1.f + e2), bv);
        const float hprev = use_h ? h_s[cur][bi_w * HH + c_base + dw] : 0.f;
        const float hn = (1.f - z) * hprev + z * htl;

        // drain everything EXCEPT this step's own poison (most recent vmem):
        // the step-(u-2) same-address poison is older => retired (see header)
        asm volatile("s_waitcnt vmcnt(1)" ::: "memory");
        __hip_atomic_store(&hring[(size_t)((u + 1) & 3) * NB * HH + wslot_off],
                           __float_as_uint(hn), __ATOMIC_RELAXED, __HIP_MEMORY_SCOPE_AGENT);
        if (ph == 0)
          text_out[((size_t)(b0 + bi_w) * TTX + t) * HH + c_base + dw] = hn;
        else if (t == T - 1)
          topic_h[(size_t)(b0 + bi_w) * HH + c_base + dw] = hn;
      }
      // no trailing barrier: 2-deep buffers tolerate one-phase skew
    }
  }
}

// ---------------------------------------------------------------------------
// attention + FC head fused (block b owns batch row b end-to-end).
//   Score phase restructured for coalescing: 8 row-groups x 32 lanes, each
//   group computes one row-dot with coalesced float4 reads + shfl reduce
//   (old version: each lane walked a 2KB-strided row => 4x L2 overfetch).
//   Context phase (coalesced already) writes into feat; then fc1/relu/fc2.
// ---------------------------------------------------------------------------
__global__ __launch_bounds__(256) void sd_att_fc(
    const float* __restrict__ text_out, const float* __restrict__ topic_h,
    const float* __restrict__ att_W, const float* __restrict__ att_b,
    const float* __restrict__ fc1_W, const float* __restrict__ fc1_b,
    const float* __restrict__ fc2_W, const float* __restrict__ fc2_b,
    float* __restrict__ logits, float* __restrict__ weights_out)
{
  __shared__ alignas(16) float aw[1024];
  __shared__ alignas(16) float th[512];
  __shared__ float sc_s[256];
  __shared__ float sred[256];
  __shared__ float wsh[256];
  __shared__ alignas(16) float feat[1024];
  __shared__ float hid[512];
  const int b = blockIdx.x, tid = threadIdx.x;

  for (int i = tid; i < 1024; i += 256) aw[i] = att_W[i];
  for (int i = tid; i < 512; i += 256) th[i] = topic_h[(size_t)b * HH + i];
  __syncthreads();

  // cb = dot(topic_h, aw[512:]) + att_b
  float part = 0.f;
  for (int i = tid; i < 512; i += 256) part += th[i] * aw[512 + i];
  sred[tid] = part;
  __syncthreads();
  for (int s = 128; s > 0; s >>= 1) { if (tid < s) sred[tid] += sred[tid + s]; __syncthreads(); }
  const float cb = sred[0] + att_b[0];
  __syncthreads();

  // scores: group gr handles rows t = rep*8 + gr, coalesced float4 reads
  const int gr = tid >> 5, ln = tid & 31;
  for (int rep = 0; rep < 32; ++rep) {
    const int t = rep * 8 + gr;
    const float* row = text_out + ((size_t)b * TTX + t) * HH;
    float p = 0.f;
#pragma unroll
    for (int j = 0; j < 4; ++j) {
      const float4 v  = *(const float4*)(row + ln * 4 + 128 * j);
      const float4 w4 = *(const float4*)(aw  + ln * 4 + 128 * j);
      p += v.x * w4.x + v.y * w4.y + v.z * w4.z + v.w * w4.w;
    }
#pragma unroll
    for (int o = 16; o > 0; o >>= 1) p += __shfl_xor(p, o, 32);
    if (ln == 0) sc_s[t] = p + cb;
  }
  __syncthreads();

  // softmax over 256 scores
  const float sc = sc_s[tid];
  sred[tid] = sc; __syncthreads();
  for (int s = 128; s > 0; s >>= 1) { if (tid < s) sred[tid] = fmaxf(sred[tid], sred[tid + s]); __syncthreads(); }
  const float m = sred[0];
  __syncthreads();
  const float e = expf(sc - m);
  sred[tid] = e; __syncthreads();
  for (int s = 128; s > 0; s >>= 1) { if (tid < s) sred[tid] += sred[tid + s]; __syncthreads(); }
  const float wv = e / sred[0];
  wsh[tid] = wv;
  weights_out[(size_t)b * TTX + tid] = wv;
  __syncthreads();

  // context -> feat[0:512] (coalesced: lanes vary dcol)
  for (int rep = 0; rep < 2; ++rep) {
    const int dcol = rep * 256 + tid;
    float accc = 0.f;
    const float* base = text_out + (size_t)b * TTX * HH + dcol;
    for (int t2 = 0; t2 < TTX; ++t2) accc += wsh[t2] * base[(size_t)t2 * HH];
    feat[dcol] = accc;
  }
  for (int i = tid; i < 512; i += 256) feat[512 + i] = th[i];
  __syncthreads();

  // fc1 + relu
  for (int rep = 0; rep < 2; ++rep) {
    const int dcol = rep * 256 + tid;
    float a = fc1_b[dcol];
#pragma unroll 4
    for (int j = 0; j < 1024; ++j) a += feat[j] * fc1_W[(size_t)j * HH + dcol];
    hid[dcol] = fmaxf(a, 0.f);
  }
  __syncthreads();

  // fc2
  float p0 = 0.f, p1 = 0.f, p2 = 0.f;
  for (int dv = tid; dv < 512; dv += 256) {
    const float hv = hid[dv];
    p0 += hv * fc2_W[dv * 3 + 0];
    p1 += hv * fc2_W[dv * 3 + 1];
    p2 += hv * fc2_W[dv * 3 + 2];
  }
  feat[tid] = p0; feat[256 + tid] = p1; feat[512 + tid] = p2;
  __syncthreads();
  for (int s = 128; s > 0; s >>= 1) {
    if (tid < s) {
      feat[tid] += feat[tid + s];
      feat[256 + tid] += feat[256 + tid + s];
      feat[512 + tid] += feat[512 + tid + s];
    }
    __syncthreads();
  }
  if (tid < 3) logits[b * 3 + tid] = feat[tid * 256] + fc2_b[tid];
}

// ---------------------------------------------------------------------------
extern "C" void kernel_launch(void* const* d_in, const int* in_sizes, int n_in,
                              void* d_out, int out_size, void* d_ws, size_t ws_size,
                              hipStream_t stream) {
  const int*   text  = (const int*)d_in[0];
  const int*   topic = (const int*)d_in[1];
  const float* emb   = (const float*)d_in[2];
  const float* tWz   = (const float*)d_in[3];
  const float* tbz   = (const float*)d_in[4];
  const float* tWo   = (const float*)d_in[5];
  const float* tbo   = (const float*)d_in[6];
  const float* pWz   = (const float*)d_in[7];
  const float* pbz   = (const float*)d_in[8];
  const float* pWo   = (const float*)d_in[9];
  const float* pbo   = (const float*)d_in[10];
  const float* attW  = (const float*)d_in[11];
  const float* attb  = (const float*)d_in[12];
  const float* fc1W  = (const float*)d_in[13];
  const float* fc1b  = (const float*)d_in[14];
  const float* fc2W  = (const float*)d_in[15];
  const float* fc2b  = (const float*)d_in[16];

  float* out = (float*)d_out;            // [0,192): logits, [192,+16384): weights
  float* ws  = (float*)d_ws;

  float* xp_text  = ws;                                    // 256*64*1024
  float* xp_topic = xp_text + (size_t)TTX * 64 * 1024;     // 16*64*1024
  float* text_o   = xp_topic + (size_t)TTP * 64 * 1024;    // 64*256*512
  float* topic_hv = text_o + (size_t)NB * TTX * HH;        // 64*512
  unsigned* hring = (unsigned*)(topic_hv + (size_t)NB * HH); // 4*64*512 u32

  // bf16 B_T buffers live in the text_o region (contiguous text|topic):
  // prep+xproj finish before sd_recur writes text_o (stream-serial) => safe.
  unsigned short* bt_text  = (unsigned short*)text_o;      // 1024*320 bf16
  unsigned short* bt_topic = bt_text + 1024 * 320;         // 1024*320 bf16

  sd_init_ring<<<dim3(4 * NB * HH / 256), dim3(256), 0, stream>>>(hring);
  sd_prep_bt<<<dim3(2560), dim3(256), 0, stream>>>(tWz, tWo, pWz, pWo, bt_text);
  sd_xproj_mfma<<<dim3(TTX + TTP, 4), dim3(256), 0, stream>>>(
      text, topic, emb, bt_text, bt_topic, tbz, tbo, pbz, pbo, xp_text, xp_topic);
  sd_recur<<<dim3(256), dim3(512), 0, stream>>>(tWz, tWo, pWz, pWo, xp_text, xp_topic,
                                                text_o, hring, topic_hv);
  sd_att_fc<<<dim3(64), dim3(256), 0, stream>>>(text_o, topic_hv, attW, attb,
                                                fc1W, fc1b, fc2W, fc2b, out, out + 192);
}

// Round 10
// 638.300 us; speedup vs baseline: 2.0590x; 1.0438x over previous
//
#include <hip/hip_runtime.h>
#include <math.h>

#define NB 64      // batch
#define TTX 256    // text timesteps
#define TTP 16     // topic timesteps
#define EE 300     // embedding dim
#define HH 512     // hidden
#define SENT16 0x7FC1u        // bf16 NaN-payload sentinel (real h never NaN)
#define SENT32 0x7FC17FC1u

typedef __attribute__((ext_vector_type(4))) float f32x4;
typedef __attribute__((ext_vector_type(8))) short short8;

__device__ __forceinline__ unsigned short bf16cvt(float f) {
  unsigned u = __float_as_uint(f);
  u += 0x7FFFu + ((u >> 16) & 1u);   // RNE
  return (unsigned short)(u >> 16);
}

// ---------------------------------------------------------------------------
// prep: (a) poison the bf16 h-ring (every call: graph-replay deterministic),
// (b) build Bt in FRAGMENT order so xproj's B-loads are fully coalesced:
//     Bt[((tile*10 + kc)*64 + lane)*8 + e] = W[k][c]  (bf16, 0-pad k>=300)
//     with k = kc*32 + 8*(lane>>4) + e, c = tile*16 + (lane&15);
//     text weights in [0, 327680), topic in [327680, 655360).
// ---------------------------------------------------------------------------
__global__ __launch_bounds__(256) void sd_prep(
    const float* __restrict__ tWz, const float* __restrict__ tWo,
    const float* __restrict__ pWz, const float* __restrict__ pWo,
    unsigned short* __restrict__ Bt, unsigned* __restrict__ ring32)
{
  const int i = blockIdx.x * 256 + threadIdx.x;   // [0, 655360)
  if (i < 4 * NB * HH / 2) ring32[i] = SENT32;    // 65536 u32 = whole ring
  const int half = 327680;
  const int j = (i < half) ? i : i - half;
  const int e    = j & 7;
  const int lane = (j >> 3) & 63;
  const int kc   = (j >> 9) % 10;
  const int tile = (j >> 9) / 10;
  const int k = kc * 32 + 8 * (lane >> 4) + e;
  const int c = tile * 16 + (lane & 15);
  const float* W = (i < half) ? ((c < 512) ? tWz : tWo)
                              : ((c < 512) ? pWz : pWo);
  const float v = (k < 300) ? W[(size_t)k * HH + (c & 511)] : 0.f;
  Bt[i] = bf16cvt(v);
}

// ---------------------------------------------------------------------------
// xproj via MFMA bf16 (r7-verified math; B-loads now fragment-coalesced:
// each short8 load is lane-contiguous 1KB per wave instead of 64-line scatter)
// ---------------------------------------------------------------------------
__global__ __launch_bounds__(256) void sd_xproj_mfma(
    const int* __restrict__ text_idx, const int* __restrict__ topic_idx,
    const float* __restrict__ emb,
    const unsigned short* __restrict__ bt_text, const unsigned short* __restrict__ bt_topic,
    const float* __restrict__ tbz, const float* __restrict__ tbo,
    const float* __restrict__ pbz, const float* __restrict__ pbo,
    float* __restrict__ xp_text, float* __restrict__ xp_topic)
{
  __shared__ alignas(16) unsigned short Als[64 * 328];
  __shared__ int tok[64];

  const bool is_text = blockIdx.x < TTX;
  const int t   = is_text ? blockIdx.x : blockIdx.x - TTX;
  const int T   = is_text ? TTX : TTP;
  const int* idx = is_text ? text_idx : topic_idx;
  const unsigned short* Bt = is_text ? bt_text : bt_topic;
  const float* bz = is_text ? tbz : pbz;
  const float* bo = is_text ? tbo : pbo;
  float* xp = is_text ? xp_text : xp_topic;

  const int tid = threadIdx.x;
  const int c0  = blockIdx.y * 256;

  if (tid < 64) tok[tid] = idx[tid * T + t];
  __syncthreads();

  {
    const int m  = tid >> 2;
    const int qt = tid & 3;
    const float* er = emb + (size_t)tok[m] * EE;
    unsigned short* ar = Als + m * 328;
    for (int j = qt; j < 75; j += 4) {
      const float4 v = *(const float4*)(er + 4 * j);
      ushort4 o;
      o.x = bf16cvt(v.x); o.y = bf16cvt(v.y);
      o.z = bf16cvt(v.z); o.w = bf16cvt(v.w);
      *(ushort4*)(ar + 4 * j) = o;
    }
    if (qt == 0) {
      for (int k = 300; k < 328; ++k) ar[k] = 0;
    }
  }
  __syncthreads();

  const int w  = tid >> 6;
  const int l  = tid & 63;
  const int lr = l & 15;
  const int lg = l >> 4;
  const int tile0 = blockIdx.y * 16 + w * 4;   // this wave's first col-tile

  f32x4 acc[4][4];
#pragma unroll
  for (int ms = 0; ms < 4; ++ms)
#pragma unroll
    for (int ns = 0; ns < 4; ++ns)
      acc[ms][ns] = (f32x4){0.f, 0.f, 0.f, 0.f};

#pragma unroll 2
  for (int kc = 0; kc < 10; ++kc) {
    short8 bfr[4];
#pragma unroll
    for (int ns = 0; ns < 4; ++ns)
      bfr[ns] = *reinterpret_cast<const short8*>(
          Bt + (((size_t)(tile0 + ns) * 10 + kc) * 64 + l) * 8);
    short8 afr[4];
#pragma unroll
    for (int ms = 0; ms < 4; ++ms)
      afr[ms] = *reinterpret_cast<const short8*>(Als + (ms * 16 + lr) * 328 + kc * 32 + 8 * lg);
#pragma unroll
    for (int ms = 0; ms < 4; ++ms)
#pragma unroll
      for (int ns = 0; ns < 4; ++ns)
        acc[ms][ns] = __builtin_amdgcn_mfma_f32_16x16x32_bf16(afr[ms], bfr[ns], acc[ms][ns], 0, 0, 0);
  }

#pragma unroll
  for (int ns = 0; ns < 4; ++ns) {
    const int cg = c0 + w * 64 + ns * 16 + lr;
    const float bias = (cg < 512) ? bz[cg] : bo[cg - 512];
#pragma unroll
    for (int ms = 0; ms < 4; ++ms) {
#pragma unroll
      for (int r = 0; r < 4; ++r) {
        const int row = ms * 16 + lg * 4 + r;
        xp[((size_t)t * 64 + row) * 1024 + cg] = acc[ms][ns][r] + bias;
      }
    }
  }
}

// ---------------------------------------------------------------------------
// Persistent recurrence kernel — r8/r9 skeleton (512 thr = 8 waves, block-
// wide sentinel poll, 2 syncs/step, vmcnt(1)) with a bf16 ring payload:
//   * ring slot = [4 rows][512 dims] bf16 (4KB); poll = ONE u64/thread;
//     staged directly into h_bf (no fp32 h_s, no convert in the poll).
//   * writers keep hprev in a REGISTER (their own previous fp32 output) —
//     bit-identical to the old h_s fp32 path.
//   * ring stores: lane pairs pack 2 bf16 into a u32 via shfl_down; even
//     threads store (one sc1 dword per pair). Poison likewise u32.
//   Protocol/proofs unchanged from r4/r9 (recycle-after-poll-success;
//   vmcnt(1) leaves only this step's own poison in flight — per-wave
//   counter, one poison instr per wave).
// ---------------------------------------------------------------------------
__global__ __launch_bounds__(512) void sd_recur(
    const float* __restrict__ tWz, const float* __restrict__ tWo,
    const float* __restrict__ pWz, const float* __restrict__ pWo,
    const float* __restrict__ xp_text, const float* __restrict__ xp_topic,
    float* __restrict__ text_out, unsigned short* __restrict__ hring,
    float* __restrict__ topic_h)
{
  __shared__ alignas(16) unsigned short h_bf[2][2080];  // bf16 h, [4 rows][520]
  __shared__ alignas(16) float red[2][2048];            // [8 wv][4 row][64 col]

  const int tid = threadIdx.x;
  const int bid = blockIdx.x;
  const int x = bid & 7;           // XCD (heuristic placement)
  const int q = bid >> 3;
  const int g = x + 8 * (q >> 4);  // batch group 0..15
  const int slice = q & 15;        // dim slice 0..15
  const int b0 = g * 4;
  const int c_base = slice * 32;

  const int wv = tid >> 6;         // wave id = k-eighth (0..7)
  const int lane = tid & 63;
  const int lg = lane >> 4;        // k-slot group 0..3
  const int l15 = lane & 15;

  const int bi_w = tid >> 5;       // writer mapping (tid<128): batch row 0..3
  const int dw = tid & 31;

  // writer thread's ring offset within a slot (bf16 units)
  const size_t wslot_off = (size_t)(b0 + bi_w) * HH + c_base + dw;

  int u = 0;  // global step counter across both phases

  for (int ph = 0; ph < 2; ++ph) {
    const float* Wz = ph ? pWz : tWz;
    const float* Wo = ph ? pWo : tWo;
    const float* xp = ph ? xp_topic : xp_text;
    const int T = ph ? TTP : TTX;

    float hprev_r = 0.f;  // writer's own h (fp32-exact), reset per phase

    // --- prep W h-part bf16 B-fragments (once per phase) ----------------
    short8 wfrag[4][2];
#pragma unroll
    for (int ns = 0; ns < 4; ++ns) {
      const float* Wg = (ns < 2) ? Wz : Wo;
      const int dim = (ns & 1) * 16 + l15;
#pragma unroll
      for (int kc = 0; kc < 2; ++kc) {
        const int kb = wv * 64 + kc * 32 + 8 * lg;
        short8 f;
#pragma unroll
        for (int e = 0; e < 8; ++e)
          f[e] = (short)bf16cvt(Wg[(size_t)(EE + kb + e) * HH + c_base + dim]);
        wfrag[ns][kc] = f;
      }
    }

    for (int t = 0; t < T; ++t, ++u) {
      const int cur = u & 1;
      const bool do_poll = (u > 0);
      const bool use_h   = (t > 0);

      float xpz = 0.f, xpo = 0.f;
      if (tid < 128) {
        const float* xpr = xp + ((size_t)t * 64 + (b0 + bi_w)) * 1024 + c_base + dw;
        xpz = xpr[0];
        xpo = xpr[512];
      }

      if (do_poll) {
        // block-wide poll-stage: one u64 (4 bf16) per thread
        const unsigned long long* src64 = (const unsigned long long*)
            (hring + (size_t)(u & 3) * NB * HH + (size_t)b0 * HH);
        unsigned long long v;
        for (;;) {
          v = __hip_atomic_load(src64 + tid, __ATOMIC_RELAXED, __HIP_MEMORY_SCOPE_AGENT);
          const unsigned lo = (unsigned)v, hi = (unsigned)(v >> 32);
          if ((lo & 0xFFFFu) != SENT16 && (lo >> 16) != SENT16 &&
              (hi & 0xFFFFu) != SENT16 && (hi >> 16) != SENT16) break;
          __builtin_amdgcn_s_sleep(1);
        }
        *(unsigned long long*)&h_bf[cur][(tid >> 7) * 520 + (tid & 127) * 4] = v;
      }

      __syncthreads();  // whole block's poll complete + stage visible

      // Safe to recycle slot (u-1)&3 now (poll success => consumers done).
      if (do_poll && tid < 128 && !(tid & 1))
        __hip_atomic_store((unsigned*)(hring + (size_t)((u - 1) & 3) * NB * HH + wslot_off),
                           SENT32, __ATOMIC_RELAXED, __HIP_MEMORY_SCOPE_AGENT);

      if (use_h) {
        const unsigned short* hb = &h_bf[cur][(lane & 3) * 520 + wv * 64 + 8 * lg];
        const short8 a0 = *reinterpret_cast<const short8*>(hb + 0);
        const short8 a1 = *reinterpret_cast<const short8*>(hb + 32);

        f32x4 acc[4];
#pragma unroll
        for (int ns = 0; ns < 4; ++ns) {
          acc[ns] = (f32x4){0.f, 0.f, 0.f, 0.f};
          acc[ns] = __builtin_amdgcn_mfma_f32_16x16x32_bf16(a0, wfrag[ns][0], acc[ns], 0, 0, 0);
          acc[ns] = __builtin_amdgcn_mfma_f32_16x16x32_bf16(a1, wfrag[ns][1], acc[ns], 0, 0, 0);
        }
        if (lane < 16) {
#pragma unroll
          for (int ns = 0; ns < 4; ++ns)
#pragma unroll
            for (int r = 0; r < 4; ++r)
              red[cur][wv * 256 + r * 64 + ns * 16 + lane] = acc[ns][r];
        }
      }

      __syncthreads();  // partials visible

      if (tid < 128) {
        float zp = 0.f, op = 0.f;
        if (use_h) {
#pragma unroll
          for (int k2 = 0; k2 < 8; ++k2) {
            zp += red[cur][k2 * 256 + bi_w * 64 + dw];        // gate z
            op += red[cur][k2 * 256 + bi_w * 64 + 32 + dw];   // gate o
          }
        }
        const float a = zp + xpz;
        const float z = 1.f / (1.f + __expf(-a));
        const float bv = op + xpo;
        const float ab = fabsf(bv);
        const float e2 = __expf(-2.f * ab);
        const float htl = __builtin_copysignf((1.f - e2) / (1.f + e2), bv);
        const float hn = (1.f - z) * hprev_r + z * htl;
        hprev_r = hn;

        // pack 2 bf16 per lane pair; even thread stores one sc1 dword
        const unsigned short hb16 = bf16cvt(hn);
        const unsigned packed = (unsigned)hb16 |
                                ((unsigned)__shfl_down((int)hb16, 1, 64) << 16);

        // drain everything EXCEPT this step's own poison (per-wave counter,
        // one poison instr) — orders the step-(u-2) same-address poison
        asm volatile("s_waitcnt vmcnt(1)" ::: "memory");
        if (!(tid & 1))
          __hip_atomic_store((unsigned*)(hring + (size_t)((u + 1) & 3) * NB * HH + wslot_off),
                             packed, __ATOMIC_RELAXED, __HIP_MEMORY_SCOPE_AGENT);
        if (ph == 0)
          text_out[((size_t)(b0 + bi_w) * TTX + t) * HH + c_base + dw] = hn;
        else if (t == T - 1)
          topic_h[(size_t)(b0 + bi_w) * HH + c_base + dw] = hn;
      }
      // no trailing barrier: 2-deep buffers tolerate one-phase skew
    }
  }
}

// ---------------------------------------------------------------------------
// attention + FC head fused (unchanged from round 9)
// ---------------------------------------------------------------------------
__global__ __launch_bounds__(256) void sd_att_fc(
    const float* __restrict__ text_out, const float* __restrict__ topic_h,
    const float* __restrict__ att_W, const float* __restrict__ att_b,
    const float* __restrict__ fc1_W, const float* __restrict__ fc1_b,
    const float* __restrict__ fc2_W, const float* __restrict__ fc2_b,
    float* __restrict__ logits, float* __restrict__ weights_out)
{
  __shared__ alignas(16) float aw[1024];
  __shared__ alignas(16) float th[512];
  __shared__ float sc_s[256];
  __shared__ float sred[256];
  __shared__ float wsh[256];
  __shared__ alignas(16) float feat[1024];
  __shared__ float hid[512];
  const int b = blockIdx.x, tid = threadIdx.x;

  for (int i = tid; i < 1024; i += 256) aw[i] = att_W[i];
  for (int i = tid; i < 512; i += 256) th[i] = topic_h[(size_t)b * HH + i];
  __syncthreads();

  float part = 0.f;
  for (int i = tid; i < 512; i += 256) part += th[i] * aw[512 + i];
  sred[tid] = part;
  __syncthreads();
  for (int s = 128; s > 0; s >>= 1) { if (tid < s) sred[tid] += sred[tid + s]; __syncthreads(); }
  const float cb = sred[0] + att_b[0];
  __syncthreads();

  const int gr = tid >> 5, ln = tid & 31;
  for (int rep = 0; rep < 32; ++rep) {
    const int t = rep * 8 + gr;
    const float* row = text_out + ((size_t)b * TTX + t) * HH;
    float p = 0.f;
#pragma unroll
    for (int j = 0; j < 4; ++j) {
      const float4 v  = *(const float4*)(row + ln * 4 + 128 * j);
      const float4 w4 = *(const float4*)(aw  + ln * 4 + 128 * j);
      p += v.x * w4.x + v.y * w4.y + v.z * w4.z + v.w * w4.w;
    }
#pragma unroll
    for (int o = 16; o > 0; o >>= 1) p += __shfl_xor(p, o, 32);
    if (ln == 0) sc_s[t] = p + cb;
  }
  __syncthreads();

  const float sc = sc_s[tid];
  sred[tid] = sc; __syncthreads();
  for (int s = 128; s > 0; s >>= 1) { if (tid < s) sred[tid] = fmaxf(sred[tid], sred[tid + s]); __syncthreads(); }
  const float m = sred[0];
  __syncthreads();
  const float e = expf(sc - m);
  sred[tid] = e; __syncthreads();
  for (int s = 128; s > 0; s >>= 1) { if (tid < s) sred[tid] += sred[tid + s]; __syncthreads(); }
  const float wv = e / sred[0];
  wsh[tid] = wv;
  weights_out[(size_t)b * TTX + tid] = wv;
  __syncthreads();

  for (int rep = 0; rep < 2; ++rep) {
    const int dcol = rep * 256 + tid;
    float accc = 0.f;
    const float* base = text_out + (size_t)b * TTX * HH + dcol;
    for (int t2 = 0; t2 < TTX; ++t2) accc += wsh[t2] * base[(size_t)t2 * HH];
    feat[dcol] = accc;
  }
  for (int i = tid; i < 512; i += 256) feat[512 + i] = th[i];
  __syncthreads();

  for (int rep = 0; rep < 2; ++rep) {
    const int dcol = rep * 256 + tid;
    float a = fc1_b[dcol];
#pragma unroll 4
    for (int j = 0; j < 1024; ++j) a += feat[j] * fc1_W[(size_t)j * HH + dcol];
    hid[dcol] = fmaxf(a, 0.f);
  }
  __syncthreads();

  float p0 = 0.f, p1 = 0.f, p2 = 0.f;
  for (int dv = tid; dv < 512; dv += 256) {
    const float hv = hid[dv];
    p0 += hv * fc2_W[dv * 3 + 0];
    p1 += hv * fc2_W[dv * 3 + 1];
    p2 += hv * fc2_W[dv * 3 + 2];
  }
  feat[tid] = p0; feat[256 + tid] = p1; feat[512 + tid] = p2;
  __syncthreads();
  for (int s = 128; s > 0; s >>= 1) {
    if (tid < s) {
      feat[tid] += feat[tid + s];
      feat[256 + tid] += feat[256 + tid + s];
      feat[512 + tid] += feat[512 + tid + s];
    }
    __syncthreads();
  }
  if (tid < 3) logits[b * 3 + tid] = feat[tid * 256] + fc2_b[tid];
}

// ---------------------------------------------------------------------------
extern "C" void kernel_launch(void* const* d_in, const int* in_sizes, int n_in,
                              void* d_out, int out_size, void* d_ws, size_t ws_size,
                              hipStream_t stream) {
  const int*   text  = (const int*)d_in[0];
  const int*   topic = (const int*)d_in[1];
  const float* emb   = (const float*)d_in[2];
  const float* tWz   = (const float*)d_in[3];
  const float* tbz   = (const float*)d_in[4];
  const float* tWo   = (const float*)d_in[5];
  const float* tbo   = (const float*)d_in[6];
  const float* pWz   = (const float*)d_in[7];
  const float* pbz   = (const float*)d_in[8];
  const float* pWo   = (const float*)d_in[9];
  const float* pbo   = (const float*)d_in[10];
  const float* attW  = (const float*)d_in[11];
  const float* attb  = (const float*)d_in[12];
  const float* fc1W  = (const float*)d_in[13];
  const float* fc1b  = (const float*)d_in[14];
  const float* fc2W  = (const float*)d_in[15];
  const float* fc2b  = (const float*)d_in[16];

  float* out = (float*)d_out;            // [0,192): logits, [192,+16384): weights
  float* ws  = (float*)d_ws;

  float* xp_text  = ws;                                    // 256*64*1024
  float* xp_topic = xp_text + (size_t)TTX * 64 * 1024;     // 16*64*1024
  float* text_o   = xp_topic + (size_t)TTP * 64 * 1024;    // 64*256*512
  float* topic_hv = text_o + (size_t)NB * TTX * HH;        // 64*512
  unsigned short* hring = (unsigned short*)(topic_hv + (size_t)NB * HH); // 4*64*512 bf16

  // bf16 fragment-order Bt buffers live in the text_o region (text|topic):
  // prep+xproj finish before sd_recur writes text_o (stream-serial) => safe.
  unsigned short* bt_text  = (unsigned short*)text_o;      // 327680 bf16
  unsigned short* bt_topic = bt_text + 327680;             // 327680 bf16

  sd_prep<<<dim3(2560), dim3(256), 0, stream>>>(tWz, tWo, pWz, pWo,
                                                bt_text, (unsigned*)hring);
  sd_xproj_mfma<<<dim3(TTX + TTP, 4), dim3(256), 0, stream>>>(
      text, topic, emb, bt_text, bt_topic, tbz, tbo, pbz, pbo, xp_text, xp_topic);
  sd_recur<<<dim3(256), dim3(512), 0, stream>>>(tWz, tWo, pWz, pWo, xp_text, xp_topic,
                                                text_o, hring, topic_hv);
  sd_att_fc<<<dim3(64), dim3(256), 0, stream>>>(text_o, topic_hv, attW, attb,
                                                fc1W, fc1b, fc2W, fc2b, out, out + 192);
}